// Round 13
// baseline (320.959 us; speedup 1.0000x reference)
//
#include <hip/hip_runtime.h>
#include <hip/hip_bf16.h>

#define B_ 4
#define C_ 64
#define N_ 4096
#define EPS_ 1e-5f
// p = exp(s*0.125) = exp2(s * 0.125*log2e); folded into Q at qkv-write time
#define C2_ 0.18033688011112042f

#if __has_builtin(__builtin_amdgcn_exp2f)
#define EXP2(x) __builtin_amdgcn_exp2f(x)
#else
#define EXP2(x) exp2f(x)
#endif

typedef __hip_bfloat16 bf16;
typedef __attribute__((ext_vector_type(8))) short short8;
typedef __attribute__((ext_vector_type(4))) float f32x4;
typedef __attribute__((ext_vector_type(16))) float f32x16;

__device__ __forceinline__ float b2f(bf16 v) { return __bfloat162float(v); }

__device__ __forceinline__ short f2bs(float f) {
  union { bf16 h; short s; } u;
  u.h = __float2bfloat16(f);
  return u.s;
}

__device__ __forceinline__ short8 pk8(const float* f) {
  union { short8 v; short s[8]; } u;
#pragma unroll
  for (int i = 0; i < 8; ++i) u.s[i] = f2bs(f[i]);
  return u.v;
}

__device__ __forceinline__ void up8(short8 v, float* d) {
  union { short8 v; unsigned u[4]; } x;
  x.v = v;
  d[0] = __uint_as_float(x.u[0] << 16);
  d[1] = __uint_as_float(x.u[0] & 0xffff0000u);
  d[2] = __uint_as_float(x.u[1] << 16);
  d[3] = __uint_as_float(x.u[1] & 0xffff0000u);
  d[4] = __uint_as_float(x.u[2] << 16);
  d[5] = __uint_as_float(x.u[2] & 0xffff0000u);
  d[6] = __uint_as_float(x.u[3] << 16);
  d[7] = __uint_as_float(x.u[3] & 0xffff0000u);
}

template <bool F32>
__device__ __forceinline__ float ldx(const void* p, size_t idx) {
  if (F32) return ((const float*)p)[idx];
  return b2f(((const bf16*)p)[idx]);
}

template <bool F32>
__device__ __forceinline__ short8 ld8(const void* p, int idx) {
  if (F32) {
    const float* fp = (const float*)p + idx;
    float tmp[8];
    *(float4*)&tmp[0] = *(const float4*)fp;
    *(float4*)&tmp[4] = *(const float4*)(fp + 4);
    return pk8(tmp);
  }
  return *(const short8*)((const bf16*)p + idx);
}

__device__ __forceinline__ f32x4 mfma32(short8 a, short8 b, f32x4 c) {
  return __builtin_amdgcn_mfma_f32_16x16x32_bf16(a, b, c, 0, 0, 0);
}
__device__ __forceinline__ f32x16 mfmaL(short8 a, short8 b, f32x16 c) {
  return __builtin_amdgcn_mfma_f32_32x32x16_bf16(a, b, c, 0, 0, 0);
}

// ---- Workspace layouts (bf16 element offsets), 32x32x16-frag native ----
// Q [b][qt32][chunk4][hi2][q'32][jj8]   (B-frag: n=l&31, k=(l>>5)*8+jj)
// K [b][kh32][chunk4][hi2][key'32][jj8] (A-frag: m=l&31, k=(l>>5)*8+jj)
// V [b][kc16][ch2][hi2][c'32][jj8], keys bit-permuted (koff bits 2<->3) so
//   the PV B-frag is cvt_pk of QK output regs in-order (no cross-lane).

// ---------------- Kernel 1: stats + integrated dtype probe ------------------
template <bool F32>
__device__ __forceinline__ void stats_sum(const void* x, int bc, int t,
                                          float& s, float& s2) {
  if (F32) {
    const float4* xp = (const float4*)((const float*)x + (size_t)bc * N_);
#pragma unroll
    for (int r = 0; r < 4; ++r) {
      const float4 v = xp[r * 256 + t];
      s += (v.x + v.y) + (v.z + v.w);
      s2 += (v.x * v.x + v.y * v.y) + (v.z * v.z + v.w * v.w);
    }
  } else {
    const bf16* xp = (const bf16*)x + (size_t)bc * N_;
#pragma unroll
    for (int r = 0; r < 2; ++r) {
      float f[8];
      up8(*(const short8*)(xp + (r * 256 + t) * 8), f);
#pragma unroll
      for (int i = 0; i < 8; ++i) { s += f[i]; s2 += f[i] * f[i]; }
    }
  }
}

__global__ __launch_bounds__(256) void k_stats(const void* __restrict__ x,
                                               float* __restrict__ meanArr,
                                               float* __restrict__ rstdArr,
                                               int* __restrict__ flag) {
  const int bc = blockIdx.x, t = threadIdx.x;
  __shared__ float ps[4], ps2[4];
  __shared__ int pflag;
  {
    const ushort* xw = (const ushort*)x + (size_t)bc * 4096;
    int cnt = 0;
#pragma unroll
    for (int j = 0; j < 4; ++j) {
      const ushort4 u = *(const ushort4*)(xw + t * 16 + j * 4);
      cnt += ((u.x >> 7) & 0xFF) >= 143;
      cnt += ((u.y >> 7) & 0xFF) >= 143;
      cnt += ((u.z >> 7) & 0xFF) >= 143;
      cnt += ((u.w >> 7) & 0xFF) >= 143;
    }
#pragma unroll
    for (int off = 32; off > 0; off >>= 1) cnt += __shfl_down(cnt, off, 64);
    if (t == 0) pflag = 0;
    __syncthreads();
    if ((t & 63) == 0 && cnt > 16) atomicAdd(&pflag, cnt);
    __syncthreads();
  }
  const bool f32 = pflag > 64;
  float s = 0.f, s2 = 0.f;
  if (f32) stats_sum<true>(x, bc, t, s, s2);
  else stats_sum<false>(x, bc, t, s, s2);
#pragma unroll
  for (int off = 32; off > 0; off >>= 1) {
    s += __shfl_down(s, off, 64);
    s2 += __shfl_down(s2, off, 64);
  }
  if ((t & 63) == 0) { ps[t >> 6] = s; ps2[t >> 6] = s2; }
  __syncthreads();
  if (t == 0) {
    const float S = (ps[0] + ps[1]) + (ps[2] + ps[3]);
    const float S2 = (ps2[0] + ps2[1]) + (ps2[2] + ps2[3]);
    const float mean = S * (1.0f / N_);
    const float var = S2 * (1.0f / N_) - mean * mean;
    meanArr[bc] = mean;
    rstdArr[bc] = rsqrtf(var + EPS_);
    flag[0] = f32 ? 1 : 0;
  }
}

// ---------------- Kernel 2: norm + qkv projection (MFMA) --------------------
// Q pre-scaled by C2_. Writes q/k/v in the 32x32-frag layouts above.
template <bool F32>
__device__ __forceinline__ void qkv_body(const void* x, const void* wqkv,
                                         const void* bqkv, const float* meanArr,
                                         const float* rstdArr, bf16* q, bf16* k,
                                         bf16* v, short* HB) {
  const int t = threadIdx.x, tj = blockIdx.x, b = blockIdx.y;
  const int n0 = tj * 64;
  {
    const int li = t & 15, nbt = (t >> 4) & 3, cg = t >> 6;
    const int n = n0 + nbt * 16 + li;
    const float* mb_ = meanArr + b * 64;
    const float* rb_ = rstdArr + b * 64;
    float hv[16];
#pragma unroll
    for (int i = 0; i < 16; ++i) {
      const int c = cg * 16 + i;
      hv[i] = (ldx<F32>(x, ((size_t)(b * 64 + c)) * N_ + n) - mb_[c]) * rb_[c];
    }
#pragma unroll
    for (int c8 = 0; c8 < 2; ++c8) {
      const int ks = cg >> 1, qd = (cg & 1) * 2 + c8;
      *(short8*)&HB[((nbt * 2 + ks) * 64 + qd * 16 + li) * 8] = pk8(&hv[c8 * 8]);
    }
  }
  __syncthreads();
  const int l = t & 63, w = t >> 6, li = l & 15, quad = l >> 4;
  short8 Wf[3][2];
#pragma unroll
  for (int sec = 0; sec < 3; ++sec)
#pragma unroll
    for (int ks = 0; ks < 2; ++ks)
      Wf[sec][ks] = ld8<F32>(wqkv, (sec * 64 + w * 16 + li) * 64 + ks * 32 + quad * 8);
  short8 Hf[4][2];
#pragma unroll
  for (int nb = 0; nb < 4; ++nb)
#pragma unroll
    for (int ks = 0; ks < 2; ++ks)
      Hf[nb][ks] = *(const short8*)&HB[((nb * 2 + ks) * 64 + l) * 8];
  float bq[4], bk[4];
#pragma unroll
  for (int r = 0; r < 4; ++r) {
    bq[r] = ldx<F32>(bqkv, w * 16 + quad * 4 + r);
    bk[r] = ldx<F32>(bqkv, 64 + w * 16 + quad * 4 + r);
  }
  const float bv = ldx<F32>(bqkv, 128 + w * 16 + li);
#pragma unroll
  for (int nb = 0; nb < 4; ++nb) {
    f32x4 dq = {0.f, 0.f, 0.f, 0.f}, dk = dq, dv = dq;
    dq = mfma32(Wf[0][0], Hf[nb][0], dq);
    dq = mfma32(Wf[0][1], Hf[nb][1], dq);
    dk = mfma32(Wf[1][0], Hf[nb][0], dk);
    dk = mfma32(Wf[1][1], Hf[nb][1], dk);
    dv = mfma32(Hf[nb][0], Wf[2][0], dv);
    dv = mfma32(Hf[nb][1], Wf[2][1], dv);
    union { ushort4 u; short s[4]; } pq, pk_, pv;
#pragma unroll
    for (int r = 0; r < 4; ++r) {
      pq.s[r] = f2bs((dq[r] + bq[r]) * C2_);
      pk_.s[r] = f2bs(dk[r] + bk[r]);
      pv.s[r] = f2bs(dv[r] + bv);
    }
    const int nbg = tj * 4 + nb;
    // q/k: lane holds X[c_out = w*16+quad*4+r][token = nb*16+li]
    const size_t qko = ((((size_t)(b * 128 + (nbg >> 1))) * 4 + w) * 2 +
                        (quad >> 1)) * 256 +
                       ((nbg & 1) * 16 + li) * 8 + (quad & 1) * 4;
    *(ushort4*)&q[qko] = pq.u;
    *(ushort4*)&k[qko] = pk_.u;
    // v: lane holds V[c_out = w*16+li][token = nb*16+quad*4+r]
    const size_t vo = ((((size_t)(b * 256 + nbg)) * 2 + (w >> 1)) * 2 +
                       (quad & 1)) * 256 +
                      ((w & 1) * 16 + li) * 8 + (quad & 2) * 2;
    *(ushort4*)&v[vo] = pv.u;
  }
}
__global__ __launch_bounds__(256) void k_qkv(
    const void* __restrict__ x, const void* __restrict__ wqkv,
    const void* __restrict__ bqkv, const float* __restrict__ meanArr,
    const float* __restrict__ rstdArr, bf16* __restrict__ q,
    bf16* __restrict__ k, bf16* __restrict__ v, const int* __restrict__ flag) {
  __shared__ short HB[4096];
  if (*flag) qkv_body<true>(x, wqkv, bqkv, meanArr, rstdArr, q, k, v, HB);
  else qkv_body<false>(x, wqkv, bqkv, meanArr, rstdArr, q, k, v, HB);
}

// ---------------- Kernel 3: barrier-free attention + proj + residual --------
// grid 256 = (b, qt64), 1024 thr / 16 waves (4 waves/SIMD — the diagnostic
// showed the old 512-thr/1-block-per-CU config left the SIMDs at 2 waves,
// 65% dependency-stall, VGPR=124 permitting 4). Wave w streams 32-key
// chunks ci = w + 16*jp (8 chunks), both query-sets; K/V fragments load
// straight to VGPRs, single-buffered, loop body identical to round 10.
// Merge: 5-level LDS tree across 16 waves. launch_bounds(1024,4) pins
// VGPR <= 128 so 16 waves/CU materialize.
template <bool F32>
__device__ __forceinline__ void attnproj_body(
    const bf16* __restrict__ qg, const bf16* __restrict__ kg,
    const bf16* __restrict__ vg, const void* __restrict__ xg,
    const void* __restrict__ wp, const void* __restrict__ bp,
    void* __restrict__ outv, float* MS, float* LSs, int b, int qt) {
  const int t = threadIdx.x, l = t & 63, w = t >> 6;
  const int hi = l >> 5, q31 = l & 31;

  short8 Qf[2][4];
#pragma unroll
  for (int qs = 0; qs < 2; ++qs)
#pragma unroll
    for (int cc = 0; cc < 4; ++cc)
      Qf[qs][cc] = *(const short8*)(qg +
          ((((size_t)(b * 128 + qt * 2 + qs)) * 4 + cc) * 2 + hi) * 256 +
          q31 * 8);

  f32x16 O[2][2];
#pragma unroll
  for (int qs = 0; qs < 2; ++qs)
#pragma unroll
    for (int ch = 0; ch < 2; ++ch)
#pragma unroll
      for (int r = 0; r < 16; ++r) O[qs][ch][r] = 0.f;
  float ls[2] = {0.f, 0.f};

  const bf16* kb = kg + ((size_t)b * 128) * 2048;  // per kh32: 4*2*256 = 2048
  const bf16* vb = vg + ((size_t)b * 256) * 1024;  // per kc16: 2*2*256 = 1024

  short8 Kf[4], Vf[4];
#pragma unroll
  for (int cc = 0; cc < 4; ++cc)
    Kf[cc] = *(const short8*)(kb + (((size_t)w * 4 + cc) * 2 + hi) * 256 + q31 * 8);
#pragma unroll
  for (int i = 0; i < 4; ++i)
    Vf[i] = *(const short8*)(vb + (((size_t)(w * 2 + (i >> 1)) * 2 + (i & 1)) * 2 + hi) * 256 + q31 * 8);

  for (int jp = 0; jp < 8; ++jp) {
    const int cn = w + 16 * (jp + 1);
    const bool pf = jp < 7;
    // ---- interleaved QK chains for both query-sets
    f32x16 sv0, sv1;
#pragma unroll
    for (int r = 0; r < 16; ++r) { sv0[r] = 0.f; sv1[r] = 0.f; }
#pragma unroll
    for (int cc = 0; cc < 4; ++cc) {
      sv0 = mfmaL(Kf[cc], Qf[0][cc], sv0);
      sv1 = mfmaL(Kf[cc], Qf[1][cc], sv1);
    }
    // ---- prefetch K(next) (Kf regs free after QK)
    if (pf) {
#pragma unroll
      for (int cc = 0; cc < 4; ++cc)
        Kf[cc] = *(const short8*)(kb + (((size_t)cn * 4 + cc) * 2 + hi) * 256 + q31 * 8);
    }
    // ---- softmax numerators (raw v_exp_f32) + bf16 pack, both query-sets
    short8 Pb0[2], Pb1[2];
    {
      float pv[16];
#pragma unroll
      for (int r = 0; r < 16; ++r) pv[r] = EXP2(sv0[r]);
      ls[0] += (((pv[0] + pv[1]) + (pv[2] + pv[3])) +
                ((pv[4] + pv[5]) + (pv[6] + pv[7]))) +
               (((pv[8] + pv[9]) + (pv[10] + pv[11])) +
                ((pv[12] + pv[13]) + (pv[14] + pv[15])));
      union { short8 v; __hip_bfloat162 h[4]; } u0, u1;
#pragma unroll
      for (int wd = 0; wd < 4; ++wd) {
        u0.h[wd] = __float22bfloat162_rn(make_float2(pv[2 * wd], pv[2 * wd + 1]));
        u1.h[wd] = __float22bfloat162_rn(make_float2(pv[8 + 2 * wd], pv[9 + 2 * wd]));
      }
      Pb0[0] = u0.v;
      Pb0[1] = u1.v;
    }
    {
      float pv[16];
#pragma unroll
      for (int r = 0; r < 16; ++r) pv[r] = EXP2(sv1[r]);
      ls[1] += (((pv[0] + pv[1]) + (pv[2] + pv[3])) +
                ((pv[4] + pv[5]) + (pv[6] + pv[7]))) +
               (((pv[8] + pv[9]) + (pv[10] + pv[11])) +
                ((pv[12] + pv[13]) + (pv[14] + pv[15])));
      union { short8 v; __hip_bfloat162 h[4]; } u0, u1;
#pragma unroll
      for (int wd = 0; wd < 4; ++wd) {
        u0.h[wd] = __float22bfloat162_rn(make_float2(pv[2 * wd], pv[2 * wd + 1]));
        u1.h[wd] = __float22bfloat162_rn(make_float2(pv[8 + 2 * wd], pv[9 + 2 * wd]));
      }
      Pb1[0] = u0.v;
      Pb1[1] = u1.v;
    }
    // ---- PV cluster (last read of Vf) under raised wave priority
    __builtin_amdgcn_s_setprio(1);
#pragma unroll
    for (int ch = 0; ch < 2; ++ch)
#pragma unroll
      for (int kc2 = 0; kc2 < 2; ++kc2) {
        O[0][ch] = mfmaL(Vf[kc2 * 2 + ch], Pb0[kc2], O[0][ch]);
        O[1][ch] = mfmaL(Vf[kc2 * 2 + ch], Pb1[kc2], O[1][ch]);
      }
    __builtin_amdgcn_s_setprio(0);
    // ---- prefetch V(next)
    if (pf) {
#pragma unroll
      for (int i = 0; i < 4; ++i)
        Vf[i] = *(const short8*)(vb + (((size_t)(cn * 2 + (i >> 1)) * 2 + (i & 1)) * 2 + hi) * 256 + q31 * 8);
    }
  }
  // lane l covers hi-half keys; lane l^32 (same q) covers the other half
#pragma unroll
  for (int qs = 0; qs < 2; ++qs) ls[qs] += __shfl_xor(ls[qs], 32, 64);

  // 5-level tree merge across 16 waves (8 LDS slots of 16KB; ls alongside)
  if (w >= 8) {
    float* S = MS + (w - 8) * 4096;
#pragma unroll
    for (int qs = 0; qs < 2; ++qs) {
#pragma unroll
      for (int ch = 0; ch < 2; ++ch)
#pragma unroll
        for (int r = 0; r < 16; ++r)
          S[((qs * 2 + ch) * 16 + r) * 64 + l] = O[qs][ch][r];
      LSs[(w - 8) * 128 + qs * 64 + l] = ls[qs];
    }
  }
  __syncthreads();
  if (w < 8) {
    const float* S = MS + w * 4096;
#pragma unroll
    for (int qs = 0; qs < 2; ++qs) {
#pragma unroll
      for (int ch = 0; ch < 2; ++ch)
#pragma unroll
        for (int r = 0; r < 16; ++r)
          O[qs][ch][r] += S[((qs * 2 + ch) * 16 + r) * 64 + l];
      ls[qs] += LSs[w * 128 + qs * 64 + l];
    }
  }
  __syncthreads();
  if (w >= 4 && w < 8) {
    float* S = MS + (w - 4) * 4096;
#pragma unroll
    for (int qs = 0; qs < 2; ++qs) {
#pragma unroll
      for (int ch = 0; ch < 2; ++ch)
#pragma unroll
        for (int r = 0; r < 16; ++r)
          S[((qs * 2 + ch) * 16 + r) * 64 + l] = O[qs][ch][r];
      LSs[(w - 4) * 128 + qs * 64 + l] = ls[qs];
    }
  }
  __syncthreads();
  if (w < 4) {
    const float* S = MS + w * 4096;
#pragma unroll
    for (int qs = 0; qs < 2; ++qs) {
#pragma unroll
      for (int ch = 0; ch < 2; ++ch)
#pragma unroll
        for (int r = 0; r < 16; ++r)
          O[qs][ch][r] += S[((qs * 2 + ch) * 16 + r) * 64 + l];
      ls[qs] += LSs[w * 128 + qs * 64 + l];
    }
  }
  __syncthreads();
  if (w == 2 || w == 3) {
    float* S = MS + (w - 2) * 4096;
#pragma unroll
    for (int qs = 0; qs < 2; ++qs) {
#pragma unroll
      for (int ch = 0; ch < 2; ++ch)
#pragma unroll
        for (int r = 0; r < 16; ++r)
          S[((qs * 2 + ch) * 16 + r) * 64 + l] = O[qs][ch][r];
      LSs[(w - 2) * 128 + qs * 64 + l] = ls[qs];
    }
  }
  __syncthreads();
  if (w < 2) {
    const float* S = MS + w * 4096;
#pragma unroll
    for (int qs = 0; qs < 2; ++qs) {
#pragma unroll
      for (int ch = 0; ch < 2; ++ch)
#pragma unroll
        for (int r = 0; r < 16; ++r)
          O[qs][ch][r] += S[((qs * 2 + ch) * 16 + r) * 64 + l];
      ls[qs] += LSs[w * 128 + qs * 64 + l];
    }
  }
  __syncthreads();
  if (w == 1) {
    float* S = MS;
#pragma unroll
    for (int qs = 0; qs < 2; ++qs) {
#pragma unroll
      for (int ch = 0; ch < 2; ++ch)
#pragma unroll
        for (int r = 0; r < 16; ++r)
          S[((qs * 2 + ch) * 16 + r) * 64 + l] = O[qs][ch][r];
      LSs[qs * 64 + l] = ls[qs];
    }
  }
  __syncthreads();
  bf16* HT = (bf16*)(MS + 2 * 4096);  // slot2 region (dead): h' [64 q][72 c]
  if (w == 0) {
    const float* S = MS;
#pragma unroll
    for (int qs = 0; qs < 2; ++qs) {
#pragma unroll
      for (int ch = 0; ch < 2; ++ch)
#pragma unroll
        for (int r = 0; r < 16; ++r)
          O[qs][ch][r] += S[((qs * 2 + ch) * 16 + r) * 64 + l];
      ls[qs] += LSs[qs * 64 + l];
      const float lv = 1.0f / ls[qs];
      const int qrow = qs * 32 + q31;
#pragma unroll
      for (int ch = 0; ch < 2; ++ch)
#pragma unroll
        for (int g = 0; g < 4; ++g) {
          union { ushort4 u; short s[4]; } pk_;
#pragma unroll
          for (int rr = 0; rr < 4; ++rr)
            pk_.s[rr] = f2bs(O[qs][ch][g * 4 + rr] * lv);
          // c = ch*32 + (r&3) + 8*(r>>2) + 4*hi
          *(ushort4*)&HT[qrow * 72 + ch * 32 + g * 8 + hi * 4] = pk_.u;
        }
    }
  }
  __syncthreads();
  // proj: out[o,n] = wp[o,:] . h'[:,n] + bp[o] + x[o,n]
  // waves 0-7: (jb o) x (qh n); waves 8-15 idle (no syncs below)
  if (w < 8) {
    const int li = l & 15, quad = l >> 4;
    const int jb = w & 3, qh = w >> 2;
    short8 Wa[2];
#pragma unroll
    for (int ks = 0; ks < 2; ++ks)
      Wa[ks] = ld8<F32>(wp, (jb * 16 + li) * 64 + ks * 32 + quad * 8);
    float bpv[4];
#pragma unroll
    for (int r = 0; r < 4; ++r) bpv[r] = ldx<F32>(bp, jb * 16 + quad * 4 + r);
#pragma unroll
    for (int nb = 0; nb < 2; ++nb) {
      short8 Hf[2];
#pragma unroll
      for (int ks = 0; ks < 2; ++ks)
        Hf[ks] = *(const short8*)&HT[(qh * 32 + nb * 16 + li) * 72 + ks * 32 + quad * 8];
      f32x4 acc = {0.f, 0.f, 0.f, 0.f};
      acc = mfma32(Wa[0], Hf[0], acc);
      acc = mfma32(Wa[1], Hf[1], acc);
#pragma unroll
      for (int r = 0; r < 4; ++r) {
        const int o = jb * 16 + quad * 4 + r;
        const int n = qt * 64 + qh * 32 + nb * 16 + li;
        const size_t idx = ((size_t)(b * 64 + o)) * N_ + n;
        const float res = ldx<F32>(xg, idx) + acc[r] + bpv[r];
        if (F32) ((float*)outv)[idx] = res;
        else ((bf16*)outv)[idx] = __float2bfloat16(res);
      }
    }
  }
}

__global__ __launch_bounds__(1024, 4) void k_attnproj(
    const bf16* __restrict__ qg, const bf16* __restrict__ kg,
    const bf16* __restrict__ vg, const void* __restrict__ xg,
    const void* __restrict__ wp, const void* __restrict__ bp,
    const int* __restrict__ flag, void* __restrict__ outv) {
  __shared__ float MS[8 * 4096];   // 128 KB merge slots (slot2 reused as HT)
  __shared__ float LSs[8 * 128];   // 4 KB ls slots
  const int bid = blockIdx.x;
  const int x = bid & 7;            // XCD: each XCD pair serves one batch
  const int b = x >> 1, qt = (bid >> 3) * 2 + (x & 1);
  if (*flag)
    attnproj_body<true>(qg, kg, vg, xg, wp, bp, outv, MS, LSs, b, qt);
  else
    attnproj_body<false>(qg, kg, vg, xg, wp, bp, outv, MS, LSs, b, qt);
}

// ---------------- launcher --------------------------------------------------
extern "C" void kernel_launch(void* const* d_in, const int* in_sizes, int n_in,
                              void* d_out, int out_size, void* d_ws,
                              size_t ws_size, hipStream_t stream) {
  const void* x = d_in[0];
  const void* wqkv = d_in[1];
  const void* bqkv = d_in[2];
  const void* wproj = d_in[3];
  const void* bproj = d_in[4];

  char* ws = (char*)d_ws;
  float* meanArr = (float*)ws;                      // 1 KB
  float* rstdArr = (float*)(ws + 1024);             // 1 KB
  int* flag = (int*)(ws + 2048);
  bf16* q = (bf16*)(ws + 4096);                     // 2 MB
  bf16* k = (bf16*)(ws + 4096 + (2u << 20));        // 2 MB
  bf16* v = (bf16*)(ws + 4096 + (4u << 20));        // 2 MB

  k_stats<<<256, 256, 0, stream>>>(x, meanArr, rstdArr, flag);
  k_qkv<<<dim3(64, 4), 256, 0, stream>>>(x, wqkv, bqkv, meanArr, rstdArr, q, k,
                                         v, flag);
  k_attnproj<<<256, 1024, 0, stream>>>(q, k, v, x, wproj, bproj, flag, d_out);
}

// Round 14
// 312.544 us; speedup vs baseline: 1.0269x; 1.0269x over previous
//
#include <hip/hip_runtime.h>
#include <hip/hip_bf16.h>

#define B_ 4
#define C_ 64
#define N_ 4096
#define EPS_ 1e-5f
// p = exp(s*0.125) = exp2(s * 0.125*log2e); folded into Q at qkv-write time
#define C2_ 0.18033688011112042f

#if __has_builtin(__builtin_amdgcn_exp2f)
#define EXP2(x) __builtin_amdgcn_exp2f(x)
#else
#define EXP2(x) exp2f(x)
#endif

typedef __hip_bfloat16 bf16;
typedef __attribute__((ext_vector_type(8))) short short8;
typedef __attribute__((ext_vector_type(4))) float f32x4;
typedef __attribute__((ext_vector_type(16))) float f32x16;

__device__ __forceinline__ float b2f(bf16 v) { return __bfloat162float(v); }

__device__ __forceinline__ short f2bs(float f) {
  union { bf16 h; short s; } u;
  u.h = __float2bfloat16(f);
  return u.s;
}

__device__ __forceinline__ short8 pk8(const float* f) {
  union { short8 v; short s[8]; } u;
#pragma unroll
  for (int i = 0; i < 8; ++i) u.s[i] = f2bs(f[i]);
  return u.v;
}

__device__ __forceinline__ void up8(short8 v, float* d) {
  union { short8 v; unsigned u[4]; } x;
  x.v = v;
  d[0] = __uint_as_float(x.u[0] << 16);
  d[1] = __uint_as_float(x.u[0] & 0xffff0000u);
  d[2] = __uint_as_float(x.u[1] << 16);
  d[3] = __uint_as_float(x.u[1] & 0xffff0000u);
  d[4] = __uint_as_float(x.u[2] << 16);
  d[5] = __uint_as_float(x.u[2] & 0xffff0000u);
  d[6] = __uint_as_float(x.u[3] << 16);
  d[7] = __uint_as_float(x.u[3] & 0xffff0000u);
}

template <bool F32>
__device__ __forceinline__ float ldx(const void* p, size_t idx) {
  if (F32) return ((const float*)p)[idx];
  return b2f(((const bf16*)p)[idx]);
}

template <bool F32>
__device__ __forceinline__ short8 ld8(const void* p, int idx) {
  if (F32) {
    const float* fp = (const float*)p + idx;
    float tmp[8];
    *(float4*)&tmp[0] = *(const float4*)fp;
    *(float4*)&tmp[4] = *(const float4*)(fp + 4);
    return pk8(tmp);
  }
  return *(const short8*)((const bf16*)p + idx);
}

__device__ __forceinline__ f32x4 mfma32(short8 a, short8 b, f32x4 c) {
  return __builtin_amdgcn_mfma_f32_16x16x32_bf16(a, b, c, 0, 0, 0);
}
__device__ __forceinline__ f32x16 mfmaL(short8 a, short8 b, f32x16 c) {
  return __builtin_amdgcn_mfma_f32_32x32x16_bf16(a, b, c, 0, 0, 0);
}

// ---- Workspace layouts (bf16 element offsets), 32x32x16-frag native ----
// Q [b][qt32][chunk4][hi2][q'32][jj8]   (B-frag: n=l&31, k=(l>>5)*8+jj)
// K [b][kh32][chunk4][hi2][key'32][jj8] (A-frag: m=l&31, k=(l>>5)*8+jj)
// V [b][kc16][ch2][hi2][c'32][jj8], keys bit-permuted (koff bits 2<->3) so
//   the PV B-frag is cvt_pk of QK output regs in-order (no cross-lane).

// ---------------- Kernel 1: stats + integrated dtype probe ------------------
template <bool F32>
__device__ __forceinline__ void stats_sum(const void* x, int bc, int t,
                                          float& s, float& s2) {
  if (F32) {
    const float4* xp = (const float4*)((const float*)x + (size_t)bc * N_);
#pragma unroll
    for (int r = 0; r < 4; ++r) {
      const float4 v = xp[r * 256 + t];
      s += (v.x + v.y) + (v.z + v.w);
      s2 += (v.x * v.x + v.y * v.y) + (v.z * v.z + v.w * v.w);
    }
  } else {
    const bf16* xp = (const bf16*)x + (size_t)bc * N_;
#pragma unroll
    for (int r = 0; r < 2; ++r) {
      float f[8];
      up8(*(const short8*)(xp + (r * 256 + t) * 8), f);
#pragma unroll
      for (int i = 0; i < 8; ++i) { s += f[i]; s2 += f[i] * f[i]; }
    }
  }
}

__global__ __launch_bounds__(256) void k_stats(const void* __restrict__ x,
                                               float* __restrict__ meanArr,
                                               float* __restrict__ rstdArr,
                                               int* __restrict__ flag) {
  const int bc = blockIdx.x, t = threadIdx.x;
  __shared__ float ps[4], ps2[4];
  __shared__ int pflag;
  {
    const ushort* xw = (const ushort*)x + (size_t)bc * 4096;
    int cnt = 0;
#pragma unroll
    for (int j = 0; j < 4; ++j) {
      const ushort4 u = *(const ushort4*)(xw + t * 16 + j * 4);
      cnt += ((u.x >> 7) & 0xFF) >= 143;
      cnt += ((u.y >> 7) & 0xFF) >= 143;
      cnt += ((u.z >> 7) & 0xFF) >= 143;
      cnt += ((u.w >> 7) & 0xFF) >= 143;
    }
#pragma unroll
    for (int off = 32; off > 0; off >>= 1) cnt += __shfl_down(cnt, off, 64);
    if (t == 0) pflag = 0;
    __syncthreads();
    if ((t & 63) == 0 && cnt > 16) atomicAdd(&pflag, cnt);
    __syncthreads();
  }
  const bool f32 = pflag > 64;
  float s = 0.f, s2 = 0.f;
  if (f32) stats_sum<true>(x, bc, t, s, s2);
  else stats_sum<false>(x, bc, t, s, s2);
#pragma unroll
  for (int off = 32; off > 0; off >>= 1) {
    s += __shfl_down(s, off, 64);
    s2 += __shfl_down(s2, off, 64);
  }
  if ((t & 63) == 0) { ps[t >> 6] = s; ps2[t >> 6] = s2; }
  __syncthreads();
  if (t == 0) {
    const float S = (ps[0] + ps[1]) + (ps[2] + ps[3]);
    const float S2 = (ps2[0] + ps2[1]) + (ps2[2] + ps2[3]);
    const float mean = S * (1.0f / N_);
    const float var = S2 * (1.0f / N_) - mean * mean;
    meanArr[bc] = mean;
    rstdArr[bc] = rsqrtf(var + EPS_);
    flag[0] = f32 ? 1 : 0;
  }
}

// ---------------- Kernel 2: norm + qkv projection (MFMA) --------------------
// Q pre-scaled by C2_. Writes q/k/v in the 32x32-frag layouts above.
template <bool F32>
__device__ __forceinline__ void qkv_body(const void* x, const void* wqkv,
                                         const void* bqkv, const float* meanArr,
                                         const float* rstdArr, bf16* q, bf16* k,
                                         bf16* v, short* HB) {
  const int t = threadIdx.x, tj = blockIdx.x, b = blockIdx.y;
  const int n0 = tj * 64;
  {
    const int li = t & 15, nbt = (t >> 4) & 3, cg = t >> 6;
    const int n = n0 + nbt * 16 + li;
    const float* mb_ = meanArr + b * 64;
    const float* rb_ = rstdArr + b * 64;
    float hv[16];
#pragma unroll
    for (int i = 0; i < 16; ++i) {
      const int c = cg * 16 + i;
      hv[i] = (ldx<F32>(x, ((size_t)(b * 64 + c)) * N_ + n) - mb_[c]) * rb_[c];
    }
#pragma unroll
    for (int c8 = 0; c8 < 2; ++c8) {
      const int ks = cg >> 1, qd = (cg & 1) * 2 + c8;
      *(short8*)&HB[((nbt * 2 + ks) * 64 + qd * 16 + li) * 8] = pk8(&hv[c8 * 8]);
    }
  }
  __syncthreads();
  const int l = t & 63, w = t >> 6, li = l & 15, quad = l >> 4;
  short8 Wf[3][2];
#pragma unroll
  for (int sec = 0; sec < 3; ++sec)
#pragma unroll
    for (int ks = 0; ks < 2; ++ks)
      Wf[sec][ks] = ld8<F32>(wqkv, (sec * 64 + w * 16 + li) * 64 + ks * 32 + quad * 8);
  short8 Hf[4][2];
#pragma unroll
  for (int nb = 0; nb < 4; ++nb)
#pragma unroll
    for (int ks = 0; ks < 2; ++ks)
      Hf[nb][ks] = *(const short8*)&HB[((nb * 2 + ks) * 64 + l) * 8];
  float bq[4], bk[4];
#pragma unroll
  for (int r = 0; r < 4; ++r) {
    bq[r] = ldx<F32>(bqkv, w * 16 + quad * 4 + r);
    bk[r] = ldx<F32>(bqkv, 64 + w * 16 + quad * 4 + r);
  }
  const float bv = ldx<F32>(bqkv, 128 + w * 16 + li);
#pragma unroll
  for (int nb = 0; nb < 4; ++nb) {
    f32x4 dq = {0.f, 0.f, 0.f, 0.f}, dk = dq, dv = dq;
    dq = mfma32(Wf[0][0], Hf[nb][0], dq);
    dq = mfma32(Wf[0][1], Hf[nb][1], dq);
    dk = mfma32(Wf[1][0], Hf[nb][0], dk);
    dk = mfma32(Wf[1][1], Hf[nb][1], dk);
    dv = mfma32(Hf[nb][0], Wf[2][0], dv);
    dv = mfma32(Hf[nb][1], Wf[2][1], dv);
    union { ushort4 u; short s[4]; } pq, pk_, pv;
#pragma unroll
    for (int r = 0; r < 4; ++r) {
      pq.s[r] = f2bs((dq[r] + bq[r]) * C2_);
      pk_.s[r] = f2bs(dk[r] + bk[r]);
      pv.s[r] = f2bs(dv[r] + bv);
    }
    const int nbg = tj * 4 + nb;
    // q/k: lane holds X[c_out = w*16+quad*4+r][token = nb*16+li]
    const size_t qko = ((((size_t)(b * 128 + (nbg >> 1))) * 4 + w) * 2 +
                        (quad >> 1)) * 256 +
                       ((nbg & 1) * 16 + li) * 8 + (quad & 1) * 4;
    *(ushort4*)&q[qko] = pq.u;
    *(ushort4*)&k[qko] = pk_.u;
    // v: lane holds V[c_out = w*16+li][token = nb*16+quad*4+r]
    const size_t vo = ((((size_t)(b * 256 + nbg)) * 2 + (w >> 1)) * 2 +
                       (quad & 1)) * 256 +
                      ((w & 1) * 16 + li) * 8 + (quad & 2) * 2;
    *(ushort4*)&v[vo] = pv.u;
  }
}
__global__ __launch_bounds__(256) void k_qkv(
    const void* __restrict__ x, const void* __restrict__ wqkv,
    const void* __restrict__ bqkv, const float* __restrict__ meanArr,
    const float* __restrict__ rstdArr, bf16* __restrict__ q,
    bf16* __restrict__ k, bf16* __restrict__ v, const int* __restrict__ flag) {
  __shared__ short HB[4096];
  if (*flag) qkv_body<true>(x, wqkv, bqkv, meanArr, rstdArr, q, k, v, HB);
  else qkv_body<false>(x, wqkv, bqkv, meanArr, rstdArr, q, k, v, HB);
}

// ---------------- Kernel 3: barrier-free attention + proj + residual --------
// grid 256 = (b, qt64), 1024 thr / 16 waves. launch_bounds(1024, 1):
// 1 block/CU => 16 waves/CU = 4 waves/SIMD, VGPR budget 128 (natural
// demand ~124 fits, NO spill — round-13's (1024,4) forced VGPR=64 and
// spilled everything: 630 MB scratch writes, 320 us). Wave w streams
// 32-key chunks ci = w + 16*jp (8 chunks), both query-sets; fragments
// straight to VGPRs, single-buffered; loop body = round-10 verified.
template <bool F32>
__device__ __forceinline__ void attnproj_body(
    const bf16* __restrict__ qg, const bf16* __restrict__ kg,
    const bf16* __restrict__ vg, const void* __restrict__ xg,
    const void* __restrict__ wp, const void* __restrict__ bp,
    void* __restrict__ outv, float* MS, float* LSs, int b, int qt) {
  const int t = threadIdx.x, l = t & 63, w = t >> 6;
  const int hi = l >> 5, q31 = l & 31;

  short8 Qf[2][4];
#pragma unroll
  for (int qs = 0; qs < 2; ++qs)
#pragma unroll
    for (int cc = 0; cc < 4; ++cc)
      Qf[qs][cc] = *(const short8*)(qg +
          ((((size_t)(b * 128 + qt * 2 + qs)) * 4 + cc) * 2 + hi) * 256 +
          q31 * 8);

  f32x16 O[2][2];
#pragma unroll
  for (int qs = 0; qs < 2; ++qs)
#pragma unroll
    for (int ch = 0; ch < 2; ++ch)
#pragma unroll
      for (int r = 0; r < 16; ++r) O[qs][ch][r] = 0.f;
  float ls[2] = {0.f, 0.f};

  const bf16* kb = kg + ((size_t)b * 128) * 2048;  // per kh32: 4*2*256 = 2048
  const bf16* vb = vg + ((size_t)b * 256) * 1024;  // per kc16: 2*2*256 = 1024

  short8 Kf[4], Vf[4];
#pragma unroll
  for (int cc = 0; cc < 4; ++cc)
    Kf[cc] = *(const short8*)(kb + (((size_t)w * 4 + cc) * 2 + hi) * 256 + q31 * 8);
#pragma unroll
  for (int i = 0; i < 4; ++i)
    Vf[i] = *(const short8*)(vb + (((size_t)(w * 2 + (i >> 1)) * 2 + (i & 1)) * 2 + hi) * 256 + q31 * 8);

  for (int jp = 0; jp < 8; ++jp) {
    const int cn = w + 16 * (jp + 1);
    const bool pf = jp < 7;
    // ---- interleaved QK chains for both query-sets
    f32x16 sv0, sv1;
#pragma unroll
    for (int r = 0; r < 16; ++r) { sv0[r] = 0.f; sv1[r] = 0.f; }
#pragma unroll
    for (int cc = 0; cc < 4; ++cc) {
      sv0 = mfmaL(Kf[cc], Qf[0][cc], sv0);
      sv1 = mfmaL(Kf[cc], Qf[1][cc], sv1);
    }
    // ---- prefetch K(next) (Kf regs free after QK)
    if (pf) {
#pragma unroll
      for (int cc = 0; cc < 4; ++cc)
        Kf[cc] = *(const short8*)(kb + (((size_t)cn * 4 + cc) * 2 + hi) * 256 + q31 * 8);
    }
    // ---- softmax numerators (raw v_exp_f32) + bf16 pack, both query-sets
    short8 Pb0[2], Pb1[2];
    {
      float pv[16];
#pragma unroll
      for (int r = 0; r < 16; ++r) pv[r] = EXP2(sv0[r]);
      ls[0] += (((pv[0] + pv[1]) + (pv[2] + pv[3])) +
                ((pv[4] + pv[5]) + (pv[6] + pv[7]))) +
               (((pv[8] + pv[9]) + (pv[10] + pv[11])) +
                ((pv[12] + pv[13]) + (pv[14] + pv[15])));
      union { short8 v; __hip_bfloat162 h[4]; } u0, u1;
#pragma unroll
      for (int wd = 0; wd < 4; ++wd) {
        u0.h[wd] = __float22bfloat162_rn(make_float2(pv[2 * wd], pv[2 * wd + 1]));
        u1.h[wd] = __float22bfloat162_rn(make_float2(pv[8 + 2 * wd], pv[9 + 2 * wd]));
      }
      Pb0[0] = u0.v;
      Pb0[1] = u1.v;
    }
    {
      float pv[16];
#pragma unroll
      for (int r = 0; r < 16; ++r) pv[r] = EXP2(sv1[r]);
      ls[1] += (((pv[0] + pv[1]) + (pv[2] + pv[3])) +
                ((pv[4] + pv[5]) + (pv[6] + pv[7]))) +
               (((pv[8] + pv[9]) + (pv[10] + pv[11])) +
                ((pv[12] + pv[13]) + (pv[14] + pv[15])));
      union { short8 v; __hip_bfloat162 h[4]; } u0, u1;
#pragma unroll
      for (int wd = 0; wd < 4; ++wd) {
        u0.h[wd] = __float22bfloat162_rn(make_float2(pv[2 * wd], pv[2 * wd + 1]));
        u1.h[wd] = __float22bfloat162_rn(make_float2(pv[8 + 2 * wd], pv[9 + 2 * wd]));
      }
      Pb1[0] = u0.v;
      Pb1[1] = u1.v;
    }
    // ---- PV cluster (last read of Vf) under raised wave priority
    __builtin_amdgcn_s_setprio(1);
#pragma unroll
    for (int ch = 0; ch < 2; ++ch)
#pragma unroll
      for (int kc2 = 0; kc2 < 2; ++kc2) {
        O[0][ch] = mfmaL(Vf[kc2 * 2 + ch], Pb0[kc2], O[0][ch]);
        O[1][ch] = mfmaL(Vf[kc2 * 2 + ch], Pb1[kc2], O[1][ch]);
      }
    __builtin_amdgcn_s_setprio(0);
    // ---- prefetch V(next)
    if (pf) {
#pragma unroll
      for (int i = 0; i < 4; ++i)
        Vf[i] = *(const short8*)(vb + (((size_t)(cn * 2 + (i >> 1)) * 2 + (i & 1)) * 2 + hi) * 256 + q31 * 8);
    }
  }
  // lane l covers hi-half keys; lane l^32 (same q) covers the other half
#pragma unroll
  for (int qs = 0; qs < 2; ++qs) ls[qs] += __shfl_xor(ls[qs], 32, 64);

  // 5-level tree merge across 16 waves (8 LDS slots of 16KB; ls alongside)
  if (w >= 8) {
    float* S = MS + (w - 8) * 4096;
#pragma unroll
    for (int qs = 0; qs < 2; ++qs) {
#pragma unroll
      for (int ch = 0; ch < 2; ++ch)
#pragma unroll
        for (int r = 0; r < 16; ++r)
          S[((qs * 2 + ch) * 16 + r) * 64 + l] = O[qs][ch][r];
      LSs[(w - 8) * 128 + qs * 64 + l] = ls[qs];
    }
  }
  __syncthreads();
  if (w < 8) {
    const float* S = MS + w * 4096;
#pragma unroll
    for (int qs = 0; qs < 2; ++qs) {
#pragma unroll
      for (int ch = 0; ch < 2; ++ch)
#pragma unroll
        for (int r = 0; r < 16; ++r)
          O[qs][ch][r] += S[((qs * 2 + ch) * 16 + r) * 64 + l];
      ls[qs] += LSs[w * 128 + qs * 64 + l];
    }
  }
  __syncthreads();
  if (w >= 4 && w < 8) {
    float* S = MS + (w - 4) * 4096;
#pragma unroll
    for (int qs = 0; qs < 2; ++qs) {
#pragma unroll
      for (int ch = 0; ch < 2; ++ch)
#pragma unroll
        for (int r = 0; r < 16; ++r)
          S[((qs * 2 + ch) * 16 + r) * 64 + l] = O[qs][ch][r];
      LSs[(w - 4) * 128 + qs * 64 + l] = ls[qs];
    }
  }
  __syncthreads();
  if (w < 4) {
    const float* S = MS + w * 4096;
#pragma unroll
    for (int qs = 0; qs < 2; ++qs) {
#pragma unroll
      for (int ch = 0; ch < 2; ++ch)
#pragma unroll
        for (int r = 0; r < 16; ++r)
          O[qs][ch][r] += S[((qs * 2 + ch) * 16 + r) * 64 + l];
      ls[qs] += LSs[w * 128 + qs * 64 + l];
    }
  }
  __syncthreads();
  if (w == 2 || w == 3) {
    float* S = MS + (w - 2) * 4096;
#pragma unroll
    for (int qs = 0; qs < 2; ++qs) {
#pragma unroll
      for (int ch = 0; ch < 2; ++ch)
#pragma unroll
        for (int r = 0; r < 16; ++r)
          S[((qs * 2 + ch) * 16 + r) * 64 + l] = O[qs][ch][r];
      LSs[(w - 2) * 128 + qs * 64 + l] = ls[qs];
    }
  }
  __syncthreads();
  if (w < 2) {
    const float* S = MS + w * 4096;
#pragma unroll
    for (int qs = 0; qs < 2; ++qs) {
#pragma unroll
      for (int ch = 0; ch < 2; ++ch)
#pragma unroll
        for (int r = 0; r < 16; ++r)
          O[qs][ch][r] += S[((qs * 2 + ch) * 16 + r) * 64 + l];
      ls[qs] += LSs[w * 128 + qs * 64 + l];
    }
  }
  __syncthreads();
  if (w == 1) {
    float* S = MS;
#pragma unroll
    for (int qs = 0; qs < 2; ++qs) {
#pragma unroll
      for (int ch = 0; ch < 2; ++ch)
#pragma unroll
        for (int r = 0; r < 16; ++r)
          S[((qs * 2 + ch) * 16 + r) * 64 + l] = O[qs][ch][r];
      LSs[qs * 64 + l] = ls[qs];
    }
  }
  __syncthreads();
  bf16* HT = (bf16*)(MS + 2 * 4096);  // slot2 region (dead): h' [64 q][72 c]
  if (w == 0) {
    const float* S = MS;
#pragma unroll
    for (int qs = 0; qs < 2; ++qs) {
#pragma unroll
      for (int ch = 0; ch < 2; ++ch)
#pragma unroll
        for (int r = 0; r < 16; ++r)
          O[qs][ch][r] += S[((qs * 2 + ch) * 16 + r) * 64 + l];
      ls[qs] += LSs[qs * 64 + l];
      const float lv = 1.0f / ls[qs];
      const int qrow = qs * 32 + q31;
#pragma unroll
      for (int ch = 0; ch < 2; ++ch)
#pragma unroll
        for (int g = 0; g < 4; ++g) {
          union { ushort4 u; short s[4]; } pk_;
#pragma unroll
          for (int rr = 0; rr < 4; ++rr)
            pk_.s[rr] = f2bs(O[qs][ch][g * 4 + rr] * lv);
          // c = ch*32 + (r&3) + 8*(r>>2) + 4*hi
          *(ushort4*)&HT[qrow * 72 + ch * 32 + g * 8 + hi * 4] = pk_.u;
        }
    }
  }
  __syncthreads();
  // proj: out[o,n] = wp[o,:] . h'[:,n] + bp[o] + x[o,n]
  // waves 0-7: (jb o) x (qh n); waves 8-15 idle (no syncs below)
  if (w < 8) {
    const int li = l & 15, quad = l >> 4;
    const int jb = w & 3, qh = w >> 2;
    short8 Wa[2];
#pragma unroll
    for (int ks = 0; ks < 2; ++ks)
      Wa[ks] = ld8<F32>(wp, (jb * 16 + li) * 64 + ks * 32 + quad * 8);
    float bpv[4];
#pragma unroll
    for (int r = 0; r < 4; ++r) bpv[r] = ldx<F32>(bp, jb * 16 + quad * 4 + r);
#pragma unroll
    for (int nb = 0; nb < 2; ++nb) {
      short8 Hf[2];
#pragma unroll
      for (int ks = 0; ks < 2; ++ks)
        Hf[ks] = *(const short8*)&HT[(qh * 32 + nb * 16 + li) * 72 + ks * 32 + quad * 8];
      f32x4 acc = {0.f, 0.f, 0.f, 0.f};
      acc = mfma32(Wa[0], Hf[0], acc);
      acc = mfma32(Wa[1], Hf[1], acc);
#pragma unroll
      for (int r = 0; r < 4; ++r) {
        const int o = jb * 16 + quad * 4 + r;
        const int n = qt * 64 + qh * 32 + nb * 16 + li;
        const size_t idx = ((size_t)(b * 64 + o)) * N_ + n;
        const float res = ldx<F32>(xg, idx) + acc[r] + bpv[r];
        if (F32) ((float*)outv)[idx] = res;
        else ((bf16*)outv)[idx] = __float2bfloat16(res);
      }
    }
  }
}

__global__ __launch_bounds__(1024, 1) void k_attnproj(
    const bf16* __restrict__ qg, const bf16* __restrict__ kg,
    const bf16* __restrict__ vg, const void* __restrict__ xg,
    const void* __restrict__ wp, const void* __restrict__ bp,
    const int* __restrict__ flag, void* __restrict__ outv) {
  __shared__ float MS[8 * 4096];   // 128 KB merge slots (slot2 reused as HT)
  __shared__ float LSs[8 * 128];   // 4 KB ls slots
  const int bid = blockIdx.x;
  const int x = bid & 7;            // XCD: each XCD pair serves one batch
  const int b = x >> 1, qt = (bid >> 3) * 2 + (x & 1);
  if (*flag)
    attnproj_body<true>(qg, kg, vg, xg, wp, bp, outv, MS, LSs, b, qt);
  else
    attnproj_body<false>(qg, kg, vg, xg, wp, bp, outv, MS, LSs, b, qt);
}

// ---------------- launcher --------------------------------------------------
extern "C" void kernel_launch(void* const* d_in, const int* in_sizes, int n_in,
                              void* d_out, int out_size, void* d_ws,
                              size_t ws_size, hipStream_t stream) {
  const void* x = d_in[0];
  const void* wqkv = d_in[1];
  const void* bqkv = d_in[2];
  const void* wproj = d_in[3];
  const void* bproj = d_in[4];

  char* ws = (char*)d_ws;
  float* meanArr = (float*)ws;                      // 1 KB
  float* rstdArr = (float*)(ws + 1024);             // 1 KB
  int* flag = (int*)(ws + 2048);
  bf16* q = (bf16*)(ws + 4096);                     // 2 MB
  bf16* k = (bf16*)(ws + 4096 + (2u << 20));        // 2 MB
  bf16* v = (bf16*)(ws + 4096 + (4u << 20));        // 2 MB

  k_stats<<<256, 256, 0, stream>>>(x, meanArr, rstdArr, flag);
  k_qkv<<<dim3(64, 4), 256, 0, stream>>>(x, wqkv, bqkv, meanArr, rstdArr, q, k,
                                         v, flag);
  k_attnproj<<<256, 1024, 0, stream>>>(q, k, v, x, wproj, bproj, flag, d_out);
}

// Round 15
// 100.315 us; speedup vs baseline: 3.1995x; 3.1156x over previous
//
#include <hip/hip_runtime.h>
#include <hip/hip_bf16.h>

#define B_ 4
#define C_ 64
#define N_ 4096
#define EPS_ 1e-5f
// p = exp(s*0.125) = exp2(s * 0.125*log2e); folded into Q at qkv-write time
#define C2_ 0.18033688011112042f

#if __has_builtin(__builtin_amdgcn_exp2f)
#define EXP2(x) __builtin_amdgcn_exp2f(x)
#else
#define EXP2(x) exp2f(x)
#endif

typedef __hip_bfloat16 bf16;
typedef __attribute__((ext_vector_type(8))) short short8;
typedef __attribute__((ext_vector_type(4))) float f32x4;
typedef __attribute__((ext_vector_type(16))) float f32x16;

__device__ __forceinline__ float b2f(bf16 v) { return __bfloat162float(v); }

__device__ __forceinline__ short f2bs(float f) {
  union { bf16 h; short s; } u;
  u.h = __float2bfloat16(f);
  return u.s;
}

__device__ __forceinline__ short8 pk8(const float* f) {
  union { short8 v; short s[8]; } u;
#pragma unroll
  for (int i = 0; i < 8; ++i) u.s[i] = f2bs(f[i]);
  return u.v;
}

__device__ __forceinline__ void up8(short8 v, float* d) {
  union { short8 v; unsigned u[4]; } x;
  x.v = v;
  d[0] = __uint_as_float(x.u[0] << 16);
  d[1] = __uint_as_float(x.u[0] & 0xffff0000u);
  d[2] = __uint_as_float(x.u[1] << 16);
  d[3] = __uint_as_float(x.u[1] & 0xffff0000u);
  d[4] = __uint_as_float(x.u[2] << 16);
  d[5] = __uint_as_float(x.u[2] & 0xffff0000u);
  d[6] = __uint_as_float(x.u[3] << 16);
  d[7] = __uint_as_float(x.u[3] & 0xffff0000u);
}

template <bool F32>
__device__ __forceinline__ float ldx(const void* p, size_t idx) {
  if (F32) return ((const float*)p)[idx];
  return b2f(((const bf16*)p)[idx]);
}

template <bool F32>
__device__ __forceinline__ short8 ld8(const void* p, int idx) {
  if (F32) {
    const float* fp = (const float*)p + idx;
    float tmp[8];
    *(float4*)&tmp[0] = *(const float4*)fp;
    *(float4*)&tmp[4] = *(const float4*)(fp + 4);
    return pk8(tmp);
  }
  return *(const short8*)((const bf16*)p + idx);
}

__device__ __forceinline__ f32x4 mfma32(short8 a, short8 b, f32x4 c) {
  return __builtin_amdgcn_mfma_f32_16x16x32_bf16(a, b, c, 0, 0, 0);
}
__device__ __forceinline__ f32x16 mfmaL(short8 a, short8 b, f32x16 c) {
  return __builtin_amdgcn_mfma_f32_32x32x16_bf16(a, b, c, 0, 0, 0);
}

// ---- Workspace layouts (bf16 element offsets), 32x32x16-frag native ----
// Q [b][qt32][chunk4][hi2][q'32][jj8]   (B-frag: n=l&31, k=(l>>5)*8+jj)
// K [b][kh32][chunk4][hi2][key'32][jj8] (A-frag: m=l&31, k=(l>>5)*8+jj)
// V [b][kc16][ch2][hi2][c'32][jj8], keys bit-permuted (koff bits 2<->3) so
//   the PV B-frag is cvt_pk of QK output regs in-order (no cross-lane).

// ---------------- Kernel 1: stats + integrated dtype probe ------------------
template <bool F32>
__device__ __forceinline__ void stats_sum(const void* x, int bc, int t,
                                          float& s, float& s2) {
  if (F32) {
    const float4* xp = (const float4*)((const float*)x + (size_t)bc * N_);
#pragma unroll
    for (int r = 0; r < 4; ++r) {
      const float4 v = xp[r * 256 + t];
      s += (v.x + v.y) + (v.z + v.w);
      s2 += (v.x * v.x + v.y * v.y) + (v.z * v.z + v.w * v.w);
    }
  } else {
    const bf16* xp = (const bf16*)x + (size_t)bc * N_;
#pragma unroll
    for (int r = 0; r < 2; ++r) {
      float f[8];
      up8(*(const short8*)(xp + (r * 256 + t) * 8), f);
#pragma unroll
      for (int i = 0; i < 8; ++i) { s += f[i]; s2 += f[i] * f[i]; }
    }
  }
}

__global__ __launch_bounds__(256) void k_stats(const void* __restrict__ x,
                                               float* __restrict__ meanArr,
                                               float* __restrict__ rstdArr,
                                               int* __restrict__ flag) {
  const int bc = blockIdx.x, t = threadIdx.x;
  __shared__ float ps[4], ps2[4];
  __shared__ int pflag;
  {
    const ushort* xw = (const ushort*)x + (size_t)bc * 4096;
    int cnt = 0;
#pragma unroll
    for (int j = 0; j < 4; ++j) {
      const ushort4 u = *(const ushort4*)(xw + t * 16 + j * 4);
      cnt += ((u.x >> 7) & 0xFF) >= 143;
      cnt += ((u.y >> 7) & 0xFF) >= 143;
      cnt += ((u.z >> 7) & 0xFF) >= 143;
      cnt += ((u.w >> 7) & 0xFF) >= 143;
    }
#pragma unroll
    for (int off = 32; off > 0; off >>= 1) cnt += __shfl_down(cnt, off, 64);
    if (t == 0) pflag = 0;
    __syncthreads();
    if ((t & 63) == 0 && cnt > 16) atomicAdd(&pflag, cnt);
    __syncthreads();
  }
  const bool f32 = pflag > 64;
  float s = 0.f, s2 = 0.f;
  if (f32) stats_sum<true>(x, bc, t, s, s2);
  else stats_sum<false>(x, bc, t, s, s2);
#pragma unroll
  for (int off = 32; off > 0; off >>= 1) {
    s += __shfl_down(s, off, 64);
    s2 += __shfl_down(s2, off, 64);
  }
  if ((t & 63) == 0) { ps[t >> 6] = s; ps2[t >> 6] = s2; }
  __syncthreads();
  if (t == 0) {
    const float S = (ps[0] + ps[1]) + (ps[2] + ps[3]);
    const float S2 = (ps2[0] + ps2[1]) + (ps2[2] + ps2[3]);
    const float mean = S * (1.0f / N_);
    const float var = S2 * (1.0f / N_) - mean * mean;
    meanArr[bc] = mean;
    rstdArr[bc] = rsqrtf(var + EPS_);
    flag[0] = f32 ? 1 : 0;
  }
}

// ---------------- Kernel 2: norm + qkv projection (MFMA) --------------------
// Q pre-scaled by C2_. Writes q/k/v in the 32x32-frag layouts above.
template <bool F32>
__device__ __forceinline__ void qkv_body(const void* x, const void* wqkv,
                                         const void* bqkv, const float* meanArr,
                                         const float* rstdArr, bf16* q, bf16* k,
                                         bf16* v, short* HB) {
  const int t = threadIdx.x, tj = blockIdx.x, b = blockIdx.y;
  const int n0 = tj * 64;
  {
    const int li = t & 15, nbt = (t >> 4) & 3, cg = t >> 6;
    const int n = n0 + nbt * 16 + li;
    const float* mb_ = meanArr + b * 64;
    const float* rb_ = rstdArr + b * 64;
    float hv[16];
#pragma unroll
    for (int i = 0; i < 16; ++i) {
      const int c = cg * 16 + i;
      hv[i] = (ldx<F32>(x, ((size_t)(b * 64 + c)) * N_ + n) - mb_[c]) * rb_[c];
    }
#pragma unroll
    for (int c8 = 0; c8 < 2; ++c8) {
      const int ks = cg >> 1, qd = (cg & 1) * 2 + c8;
      *(short8*)&HB[((nbt * 2 + ks) * 64 + qd * 16 + li) * 8] = pk8(&hv[c8 * 8]);
    }
  }
  __syncthreads();
  const int l = t & 63, w = t >> 6, li = l & 15, quad = l >> 4;
  short8 Wf[3][2];
#pragma unroll
  for (int sec = 0; sec < 3; ++sec)
#pragma unroll
    for (int ks = 0; ks < 2; ++ks)
      Wf[sec][ks] = ld8<F32>(wqkv, (sec * 64 + w * 16 + li) * 64 + ks * 32 + quad * 8);
  short8 Hf[4][2];
#pragma unroll
  for (int nb = 0; nb < 4; ++nb)
#pragma unroll
    for (int ks = 0; ks < 2; ++ks)
      Hf[nb][ks] = *(const short8*)&HB[((nb * 2 + ks) * 64 + l) * 8];
  float bq[4], bk[4];
#pragma unroll
  for (int r = 0; r < 4; ++r) {
    bq[r] = ldx<F32>(bqkv, w * 16 + quad * 4 + r);
    bk[r] = ldx<F32>(bqkv, 64 + w * 16 + quad * 4 + r);
  }
  const float bv = ldx<F32>(bqkv, 128 + w * 16 + li);
#pragma unroll
  for (int nb = 0; nb < 4; ++nb) {
    f32x4 dq = {0.f, 0.f, 0.f, 0.f}, dk = dq, dv = dq;
    dq = mfma32(Wf[0][0], Hf[nb][0], dq);
    dq = mfma32(Wf[0][1], Hf[nb][1], dq);
    dk = mfma32(Wf[1][0], Hf[nb][0], dk);
    dk = mfma32(Wf[1][1], Hf[nb][1], dk);
    dv = mfma32(Hf[nb][0], Wf[2][0], dv);
    dv = mfma32(Hf[nb][1], Wf[2][1], dv);
    union { ushort4 u; short s[4]; } pq, pk_, pv;
#pragma unroll
    for (int r = 0; r < 4; ++r) {
      pq.s[r] = f2bs((dq[r] + bq[r]) * C2_);
      pk_.s[r] = f2bs(dk[r] + bk[r]);
      pv.s[r] = f2bs(dv[r] + bv);
    }
    const int nbg = tj * 4 + nb;
    // q/k: lane holds X[c_out = w*16+quad*4+r][token = nb*16+li]
    const size_t qko = ((((size_t)(b * 128 + (nbg >> 1))) * 4 + w) * 2 +
                        (quad >> 1)) * 256 +
                       ((nbg & 1) * 16 + li) * 8 + (quad & 1) * 4;
    *(ushort4*)&q[qko] = pq.u;
    *(ushort4*)&k[qko] = pk_.u;
    // v: lane holds V[c_out = w*16+li][token = nb*16+quad*4+r]
    const size_t vo = ((((size_t)(b * 256 + nbg)) * 2 + (w >> 1)) * 2 +
                       (quad & 1)) * 256 +
                      ((w & 1) * 16 + li) * 8 + (quad & 2) * 2;
    *(ushort4*)&v[vo] = pv.u;
  }
}
__global__ __launch_bounds__(256) void k_qkv(
    const void* __restrict__ x, const void* __restrict__ wqkv,
    const void* __restrict__ bqkv, const float* __restrict__ meanArr,
    const float* __restrict__ rstdArr, bf16* __restrict__ q,
    bf16* __restrict__ k, bf16* __restrict__ v, const int* __restrict__ flag) {
  __shared__ short HB[4096];
  if (*flag) qkv_body<true>(x, wqkv, bqkv, meanArr, rstdArr, q, k, v, HB);
  else qkv_body<false>(x, wqkv, bqkv, meanArr, rstdArr, q, k, v, HB);
}

// ---------------- Kernel 3: attention partials (key-split) ------------------
// grid 512 = (b, kh2, qt64), 512 thr / 8 waves, launch_bounds(512,2):
// VGPR=124 verified, 2 blocks/CU -> 16 waves/CU = 4 waves/SIMD (the lever
// rounds 12-14 isolated), L2 traffic unchanged (each block reads HALF of
// K/V: 512 KB; 512 blocks x 0.5 MB = 256 MB total, same as before).
// Loop body = round-10 verified. Block writes f32 partial O ([c][q]-major,
// coalesced) + partial ls to workspace; k_merge finishes.
__global__ __launch_bounds__(512, 2) void k_attn(
    const bf16* __restrict__ qg, const bf16* __restrict__ kg,
    const bf16* __restrict__ vg, float* __restrict__ opartF,
    float* __restrict__ lpartF) {
  __shared__ float MS[4 * 4096];   // 64 KB merge slots
  __shared__ float LSs[4 * 128];
  const int bid = blockIdx.x;
  const int xx = bid & 7;           // XCD swizzle: (b, kh2) pinned per XCD
  const int b = xx >> 1, kh2 = xx & 1, qt = bid >> 3;
  const int t = threadIdx.x, l = t & 63, w = t >> 6;
  const int hi = l >> 5, q31 = l & 31;

  short8 Qf[2][4];
#pragma unroll
  for (int qs = 0; qs < 2; ++qs)
#pragma unroll
    for (int cc = 0; cc < 4; ++cc)
      Qf[qs][cc] = *(const short8*)(qg +
          ((((size_t)(b * 128 + qt * 2 + qs)) * 4 + cc) * 2 + hi) * 256 +
          q31 * 8);

  f32x16 O[2][2];
#pragma unroll
  for (int qs = 0; qs < 2; ++qs)
#pragma unroll
    for (int ch = 0; ch < 2; ++ch)
#pragma unroll
      for (int r = 0; r < 16; ++r) O[qs][ch][r] = 0.f;
  float ls[2] = {0.f, 0.f};

  const bf16* kb = kg + ((size_t)b * 128) * 2048;  // per kh32: 4*2*256 = 2048
  const bf16* vb = vg + ((size_t)b * 256) * 1024;  // per kc16: 2*2*256 = 1024
  const int c0 = kh2 * 64;                         // this block's chunk base

  short8 Kf[4], Vf[4];
  {
    const int ci = c0 + w;
#pragma unroll
    for (int cc = 0; cc < 4; ++cc)
      Kf[cc] = *(const short8*)(kb + (((size_t)ci * 4 + cc) * 2 + hi) * 256 + q31 * 8);
#pragma unroll
    for (int i = 0; i < 4; ++i)
      Vf[i] = *(const short8*)(vb + (((size_t)(ci * 2 + (i >> 1)) * 2 + (i & 1)) * 2 + hi) * 256 + q31 * 8);
  }

  for (int jp = 0; jp < 8; ++jp) {
    const int cn = c0 + w + 8 * (jp + 1);
    const bool pf = jp < 7;
    // ---- interleaved QK chains for both query-sets
    f32x16 sv0, sv1;
#pragma unroll
    for (int r = 0; r < 16; ++r) { sv0[r] = 0.f; sv1[r] = 0.f; }
#pragma unroll
    for (int cc = 0; cc < 4; ++cc) {
      sv0 = mfmaL(Kf[cc], Qf[0][cc], sv0);
      sv1 = mfmaL(Kf[cc], Qf[1][cc], sv1);
    }
    // ---- prefetch K(next) (Kf regs free after QK)
    if (pf) {
#pragma unroll
      for (int cc = 0; cc < 4; ++cc)
        Kf[cc] = *(const short8*)(kb + (((size_t)cn * 4 + cc) * 2 + hi) * 256 + q31 * 8);
    }
    // ---- softmax numerators (raw v_exp_f32) + bf16 pack, both query-sets
    short8 Pb0[2], Pb1[2];
    {
      float pv[16];
#pragma unroll
      for (int r = 0; r < 16; ++r) pv[r] = EXP2(sv0[r]);
      ls[0] += (((pv[0] + pv[1]) + (pv[2] + pv[3])) +
                ((pv[4] + pv[5]) + (pv[6] + pv[7]))) +
               (((pv[8] + pv[9]) + (pv[10] + pv[11])) +
                ((pv[12] + pv[13]) + (pv[14] + pv[15])));
      union { short8 v; __hip_bfloat162 h[4]; } u0, u1;
#pragma unroll
      for (int wd = 0; wd < 4; ++wd) {
        u0.h[wd] = __float22bfloat162_rn(make_float2(pv[2 * wd], pv[2 * wd + 1]));
        u1.h[wd] = __float22bfloat162_rn(make_float2(pv[8 + 2 * wd], pv[9 + 2 * wd]));
      }
      Pb0[0] = u0.v;
      Pb0[1] = u1.v;
    }
    {
      float pv[16];
#pragma unroll
      for (int r = 0; r < 16; ++r) pv[r] = EXP2(sv1[r]);
      ls[1] += (((pv[0] + pv[1]) + (pv[2] + pv[3])) +
                ((pv[4] + pv[5]) + (pv[6] + pv[7]))) +
               (((pv[8] + pv[9]) + (pv[10] + pv[11])) +
                ((pv[12] + pv[13]) + (pv[14] + pv[15])));
      union { short8 v; __hip_bfloat162 h[4]; } u0, u1;
#pragma unroll
      for (int wd = 0; wd < 4; ++wd) {
        u0.h[wd] = __float22bfloat162_rn(make_float2(pv[2 * wd], pv[2 * wd + 1]));
        u1.h[wd] = __float22bfloat162_rn(make_float2(pv[8 + 2 * wd], pv[9 + 2 * wd]));
      }
      Pb1[0] = u0.v;
      Pb1[1] = u1.v;
    }
    // ---- PV cluster (last read of Vf) under raised wave priority
    __builtin_amdgcn_s_setprio(1);
#pragma unroll
    for (int ch = 0; ch < 2; ++ch)
#pragma unroll
      for (int kc2 = 0; kc2 < 2; ++kc2) {
        O[0][ch] = mfmaL(Vf[kc2 * 2 + ch], Pb0[kc2], O[0][ch]);
        O[1][ch] = mfmaL(Vf[kc2 * 2 + ch], Pb1[kc2], O[1][ch]);
      }
    __builtin_amdgcn_s_setprio(0);
    // ---- prefetch V(next)
    if (pf) {
#pragma unroll
      for (int i = 0; i < 4; ++i)
        Vf[i] = *(const short8*)(vb + (((size_t)(cn * 2 + (i >> 1)) * 2 + (i & 1)) * 2 + hi) * 256 + q31 * 8);
    }
  }
  // lane l covers hi-half keys; lane l^32 (same q) covers the other half
#pragma unroll
  for (int qs = 0; qs < 2; ++qs) ls[qs] += __shfl_xor(ls[qs], 32, 64);

  // 3-level tree merge across 8 waves (as round 10, verified)
  if (w >= 4) {
    float* S = MS + (w - 4) * 4096;
#pragma unroll
    for (int qs = 0; qs < 2; ++qs) {
#pragma unroll
      for (int ch = 0; ch < 2; ++ch)
#pragma unroll
        for (int r = 0; r < 16; ++r)
          S[((qs * 2 + ch) * 16 + r) * 64 + l] = O[qs][ch][r];
      LSs[(w - 4) * 128 + qs * 64 + l] = ls[qs];
    }
  }
  __syncthreads();
  if (w < 4) {
    const float* S = MS + w * 4096;
#pragma unroll
    for (int qs = 0; qs < 2; ++qs) {
#pragma unroll
      for (int ch = 0; ch < 2; ++ch)
#pragma unroll
        for (int r = 0; r < 16; ++r)
          O[qs][ch][r] += S[((qs * 2 + ch) * 16 + r) * 64 + l];
      ls[qs] += LSs[w * 128 + qs * 64 + l];
    }
  }
  __syncthreads();
  if (w == 2 || w == 3) {
    float* S = MS + (w - 2) * 4096;
#pragma unroll
    for (int qs = 0; qs < 2; ++qs) {
#pragma unroll
      for (int ch = 0; ch < 2; ++ch)
#pragma unroll
        for (int r = 0; r < 16; ++r)
          S[((qs * 2 + ch) * 16 + r) * 64 + l] = O[qs][ch][r];
      LSs[(w - 2) * 128 + qs * 64 + l] = ls[qs];
    }
  }
  __syncthreads();
  if (w < 2) {
    const float* S = MS + w * 4096;
#pragma unroll
    for (int qs = 0; qs < 2; ++qs) {
#pragma unroll
      for (int ch = 0; ch < 2; ++ch)
#pragma unroll
        for (int r = 0; r < 16; ++r)
          O[qs][ch][r] += S[((qs * 2 + ch) * 16 + r) * 64 + l];
      ls[qs] += LSs[w * 128 + qs * 64 + l];
    }
  }
  __syncthreads();
  if (w == 1) {
    float* S = MS;
#pragma unroll
    for (int qs = 0; qs < 2; ++qs) {
#pragma unroll
      for (int ch = 0; ch < 2; ++ch)
#pragma unroll
        for (int r = 0; r < 16; ++r)
          S[((qs * 2 + ch) * 16 + r) * 64 + l] = O[qs][ch][r];
      LSs[qs * 64 + l] = ls[qs];
    }
  }
  __syncthreads();
  if (w == 0) {
    // final sum + write partial: po layout [c64][q64] f32 (lanes -> contiguous q)
    float* po = opartF + ((((size_t)(b * 64 + qt)) * 2 + kh2) << 12);
    float* lp = lpartF + ((((size_t)(b * 64 + qt)) * 2 + kh2) << 6);
    const float* S = MS;
#pragma unroll
    for (int qs = 0; qs < 2; ++qs) {
#pragma unroll
      for (int ch = 0; ch < 2; ++ch)
#pragma unroll
        for (int r = 0; r < 16; ++r) {
          const float v = O[qs][ch][r] + S[((qs * 2 + ch) * 16 + r) * 64 + l];
          const int c = ch * 32 + (r >> 2) * 8 + hi * 4 + (r & 3);
          po[c * 64 + qs * 32 + q31] = v;
        }
      ls[qs] += LSs[qs * 64 + l];
      if (l < 32) lp[qs * 32 + l] = ls[qs];
    }
  }
}

// ---------------- Kernel 4: merge halves + proj + residual ------------------
template <bool F32>
__device__ __forceinline__ void merge_body(const float* opartF,
                                           const float* lpartF, const void* xg,
                                           const void* wp, const void* bp,
                                           void* outv, bf16* HT, float* LD,
                                           int qt, int b) {
  const int t = threadIdx.x;
  const size_t pb = ((size_t)(b * 64 + qt)) * 2;
  const float* p0 = opartF + (pb << 12);
  const float* p1 = p0 + 4096;
  const float* l0 = lpartF + (pb << 6);
  if (t < 64) LD[t] = 1.0f / (l0[t] + l0[64 + t]);
  __syncthreads();
  {
    const int c = t & 63, qg = (t >> 6) * 16;
    float s[16];
#pragma unroll
    for (int j4 = 0; j4 < 4; ++j4) {
      const float4 a = *(const float4*)(p0 + c * 64 + qg + j4 * 4);
      const float4 bb = *(const float4*)(p1 + c * 64 + qg + j4 * 4);
      s[j4 * 4 + 0] = a.x + bb.x;
      s[j4 * 4 + 1] = a.y + bb.y;
      s[j4 * 4 + 2] = a.z + bb.z;
      s[j4 * 4 + 3] = a.w + bb.w;
    }
#pragma unroll
    for (int j = 0; j < 16; ++j)
      HT[(qg + j) * 72 + c] = __float2bfloat16(s[j] * LD[qg + j]);
  }
  __syncthreads();
  // proj: out[o,n] = wp[o,:] . h'[:,n] + bp[o] + x[o,n]; 4 waves = o-rows
  const int l = t & 63, w = t >> 6, li = l & 15, quad = l >> 4;
  short8 Wa[2];
#pragma unroll
  for (int ks = 0; ks < 2; ++ks)
    Wa[ks] = ld8<F32>(wp, (w * 16 + li) * 64 + ks * 32 + quad * 8);
  float bpv[4];
#pragma unroll
  for (int r = 0; r < 4; ++r) bpv[r] = ldx<F32>(bp, w * 16 + quad * 4 + r);
#pragma unroll
  for (int qh = 0; qh < 2; ++qh)
#pragma unroll
    for (int nb = 0; nb < 2; ++nb) {
      short8 Hf[2];
#pragma unroll
      for (int ks = 0; ks < 2; ++ks)
        Hf[ks] = *(const short8*)&HT[(qh * 32 + nb * 16 + li) * 72 + ks * 32 + quad * 8];
      f32x4 acc = {0.f, 0.f, 0.f, 0.f};
      acc = mfma32(Wa[0], Hf[0], acc);
      acc = mfma32(Wa[1], Hf[1], acc);
#pragma unroll
      for (int r = 0; r < 4; ++r) {
        const int o = w * 16 + quad * 4 + r;
        const int n = qt * 64 + qh * 32 + nb * 16 + li;
        const size_t idx = ((size_t)(b * 64 + o)) * N_ + n;
        const float res = ldx<F32>(xg, idx) + acc[r] + bpv[r];
        if (F32) ((float*)outv)[idx] = res;
        else ((bf16*)outv)[idx] = __float2bfloat16(res);
      }
    }
}

__global__ __launch_bounds__(256) void k_merge(
    const float* __restrict__ opartF, const float* __restrict__ lpartF,
    const void* __restrict__ xg, const void* __restrict__ wp,
    const void* __restrict__ bp, const int* __restrict__ flag,
    void* __restrict__ outv) {
  __shared__ bf16 HT[64 * 72];
  __shared__ float LD[64];
  const int qt = blockIdx.x, b = blockIdx.y;
  if (*flag)
    merge_body<true>(opartF, lpartF, xg, wp, bp, outv, HT, LD, qt, b);
  else
    merge_body<false>(opartF, lpartF, xg, wp, bp, outv, HT, LD, qt, b);
}

// ---------------- launcher --------------------------------------------------
extern "C" void kernel_launch(void* const* d_in, const int* in_sizes, int n_in,
                              void* d_out, int out_size, void* d_ws,
                              size_t ws_size, hipStream_t stream) {
  const void* x = d_in[0];
  const void* wqkv = d_in[1];
  const void* bqkv = d_in[2];
  const void* wproj = d_in[3];
  const void* bproj = d_in[4];

  char* ws = (char*)d_ws;
  float* meanArr = (float*)ws;                       // 1 KB
  float* rstdArr = (float*)(ws + 1024);              // 1 KB
  int* flag = (int*)(ws + 2048);
  bf16* q = (bf16*)(ws + 4096);                      // 2 MB
  bf16* k = (bf16*)(ws + 4096 + (2u << 20));         // 2 MB
  bf16* v = (bf16*)(ws + 4096 + (4u << 20));         // 2 MB
  float* opartF = (float*)(ws + 4096 + (6u << 20));  // 8 MB f32 partials
  float* lpartF = (float*)(ws + 4096 + (14u << 20)); // 128 KB partial ls

  k_stats<<<256, 256, 0, stream>>>(x, meanArr, rstdArr, flag);
  k_qkv<<<dim3(64, 4), 256, 0, stream>>>(x, wqkv, bqkv, meanArr, rstdArr, q, k,
                                         v, flag);
  k_attn<<<512, 512, 0, stream>>>(q, k, v, opartF, lpartF);
  k_merge<<<dim3(64, 4), 256, 0, stream>>>(opartF, lpartF, x, wproj, bproj,
                                           flag, d_out);
}

// Round 16
// 92.645 us; speedup vs baseline: 3.4644x; 1.0828x over previous
//
#include <hip/hip_runtime.h>
#include <hip/hip_bf16.h>

#define B_ 4
#define C_ 64
#define N_ 4096
#define EPS_ 1e-5f
// p = exp(s*0.125) = exp2(s * 0.125*log2e); folded into Q at qkv-write time
#define C2_ 0.18033688011112042f

#if __has_builtin(__builtin_amdgcn_exp2f)
#define EXP2(x) __builtin_amdgcn_exp2f(x)
#else
#define EXP2(x) exp2f(x)
#endif

typedef __hip_bfloat16 bf16;
typedef __attribute__((ext_vector_type(8))) short short8;
typedef __attribute__((ext_vector_type(4))) float f32x4;
typedef __attribute__((ext_vector_type(16))) float f32x16;

__device__ __forceinline__ float b2f(bf16 v) { return __bfloat162float(v); }

__device__ __forceinline__ short f2bs(float f) {
  union { bf16 h; short s; } u;
  u.h = __float2bfloat16(f);
  return u.s;
}

__device__ __forceinline__ short8 pk8(const float* f) {
  union { short8 v; short s[8]; } u;
#pragma unroll
  for (int i = 0; i < 8; ++i) u.s[i] = f2bs(f[i]);
  return u.v;
}

__device__ __forceinline__ void up8(short8 v, float* d) {
  union { short8 v; unsigned u[4]; } x;
  x.v = v;
  d[0] = __uint_as_float(x.u[0] << 16);
  d[1] = __uint_as_float(x.u[0] & 0xffff0000u);
  d[2] = __uint_as_float(x.u[1] << 16);
  d[3] = __uint_as_float(x.u[1] & 0xffff0000u);
  d[4] = __uint_as_float(x.u[2] << 16);
  d[5] = __uint_as_float(x.u[2] & 0xffff0000u);
  d[6] = __uint_as_float(x.u[3] << 16);
  d[7] = __uint_as_float(x.u[3] & 0xffff0000u);
}

template <bool F32>
__device__ __forceinline__ float ldx(const void* p, size_t idx) {
  if (F32) return ((const float*)p)[idx];
  return b2f(((const bf16*)p)[idx]);
}

template <bool F32>
__device__ __forceinline__ short8 ld8(const void* p, int idx) {
  if (F32) {
    const float* fp = (const float*)p + idx;
    float tmp[8];
    *(float4*)&tmp[0] = *(const float4*)fp;
    *(float4*)&tmp[4] = *(const float4*)(fp + 4);
    return pk8(tmp);
  }
  return *(const short8*)((const bf16*)p + idx);
}

__device__ __forceinline__ f32x4 mfma32(short8 a, short8 b, f32x4 c) {
  return __builtin_amdgcn_mfma_f32_16x16x32_bf16(a, b, c, 0, 0, 0);
}
__device__ __forceinline__ f32x16 mfmaL(short8 a, short8 b, f32x16 c) {
  return __builtin_amdgcn_mfma_f32_32x32x16_bf16(a, b, c, 0, 0, 0);
}

// ---- Workspace layouts (bf16 element offsets), 32x32x16-frag native ----
// Q [b][qt32][chunk4][hi2][q'32][jj8]   (B-frag: n=l&31, k=(l>>5)*8+jj)
// K [b][kh32][chunk4][hi2][key'32][jj8] (A-frag: m=l&31, k=(l>>5)*8+jj)
// V [b][kc16][ch2][hi2][c'32][jj8], keys bit-permuted (koff bits 2<->3) so
//   the PV B-frag is cvt_pk of QK output regs in-order (no cross-lane).

// ---------------- Kernel 1: stats + integrated dtype probe ------------------
template <bool F32>
__device__ __forceinline__ void stats_sum(const void* x, int bc, int t,
                                          float& s, float& s2) {
  if (F32) {
    const float4* xp = (const float4*)((const float*)x + (size_t)bc * N_);
#pragma unroll
    for (int r = 0; r < 4; ++r) {
      const float4 v = xp[r * 256 + t];
      s += (v.x + v.y) + (v.z + v.w);
      s2 += (v.x * v.x + v.y * v.y) + (v.z * v.z + v.w * v.w);
    }
  } else {
    const bf16* xp = (const bf16*)x + (size_t)bc * N_;
#pragma unroll
    for (int r = 0; r < 2; ++r) {
      float f[8];
      up8(*(const short8*)(xp + (r * 256 + t) * 8), f);
#pragma unroll
      for (int i = 0; i < 8; ++i) { s += f[i]; s2 += f[i] * f[i]; }
    }
  }
}

__global__ __launch_bounds__(256) void k_stats(const void* __restrict__ x,
                                               float* __restrict__ meanArr,
                                               float* __restrict__ rstdArr,
                                               int* __restrict__ flag) {
  const int bc = blockIdx.x, t = threadIdx.x;
  __shared__ float ps[4], ps2[4];
  __shared__ int pflag;
  {
    const ushort* xw = (const ushort*)x + (size_t)bc * 4096;
    int cnt = 0;
#pragma unroll
    for (int j = 0; j < 4; ++j) {
      const ushort4 u = *(const ushort4*)(xw + t * 16 + j * 4);
      cnt += ((u.x >> 7) & 0xFF) >= 143;
      cnt += ((u.y >> 7) & 0xFF) >= 143;
      cnt += ((u.z >> 7) & 0xFF) >= 143;
      cnt += ((u.w >> 7) & 0xFF) >= 143;
    }
#pragma unroll
    for (int off = 32; off > 0; off >>= 1) cnt += __shfl_down(cnt, off, 64);
    if (t == 0) pflag = 0;
    __syncthreads();
    if ((t & 63) == 0 && cnt > 16) atomicAdd(&pflag, cnt);
    __syncthreads();
  }
  const bool f32 = pflag > 64;
  float s = 0.f, s2 = 0.f;
  if (f32) stats_sum<true>(x, bc, t, s, s2);
  else stats_sum<false>(x, bc, t, s, s2);
#pragma unroll
  for (int off = 32; off > 0; off >>= 1) {
    s += __shfl_down(s, off, 64);
    s2 += __shfl_down(s2, off, 64);
  }
  if ((t & 63) == 0) { ps[t >> 6] = s; ps2[t >> 6] = s2; }
  __syncthreads();
  if (t == 0) {
    const float S = (ps[0] + ps[1]) + (ps[2] + ps[3]);
    const float S2 = (ps2[0] + ps2[1]) + (ps2[2] + ps2[3]);
    const float mean = S * (1.0f / N_);
    const float var = S2 * (1.0f / N_) - mean * mean;
    meanArr[bc] = mean;
    rstdArr[bc] = rsqrtf(var + EPS_);
    flag[0] = f32 ? 1 : 0;
  }
}

// ---------------- Kernel 2: norm + qkv projection (MFMA) --------------------
// Q pre-scaled by C2_. Writes q/k/v in the 32x32-frag layouts above.
template <bool F32>
__device__ __forceinline__ void qkv_body(const void* x, const void* wqkv,
                                         const void* bqkv, const float* meanArr,
                                         const float* rstdArr, bf16* q, bf16* k,
                                         bf16* v, short* HB) {
  const int t = threadIdx.x, tj = blockIdx.x, b = blockIdx.y;
  const int n0 = tj * 64;
  {
    const int li = t & 15, nbt = (t >> 4) & 3, cg = t >> 6;
    const int n = n0 + nbt * 16 + li;
    const float* mb_ = meanArr + b * 64;
    const float* rb_ = rstdArr + b * 64;
    float hv[16];
#pragma unroll
    for (int i = 0; i < 16; ++i) {
      const int c = cg * 16 + i;
      hv[i] = (ldx<F32>(x, ((size_t)(b * 64 + c)) * N_ + n) - mb_[c]) * rb_[c];
    }
#pragma unroll
    for (int c8 = 0; c8 < 2; ++c8) {
      const int ks = cg >> 1, qd = (cg & 1) * 2 + c8;
      *(short8*)&HB[((nbt * 2 + ks) * 64 + qd * 16 + li) * 8] = pk8(&hv[c8 * 8]);
    }
  }
  __syncthreads();
  const int l = t & 63, w = t >> 6, li = l & 15, quad = l >> 4;
  short8 Wf[3][2];
#pragma unroll
  for (int sec = 0; sec < 3; ++sec)
#pragma unroll
    for (int ks = 0; ks < 2; ++ks)
      Wf[sec][ks] = ld8<F32>(wqkv, (sec * 64 + w * 16 + li) * 64 + ks * 32 + quad * 8);
  short8 Hf[4][2];
#pragma unroll
  for (int nb = 0; nb < 4; ++nb)
#pragma unroll
    for (int ks = 0; ks < 2; ++ks)
      Hf[nb][ks] = *(const short8*)&HB[((nb * 2 + ks) * 64 + l) * 8];
  float bq[4], bk[4];
#pragma unroll
  for (int r = 0; r < 4; ++r) {
    bq[r] = ldx<F32>(bqkv, w * 16 + quad * 4 + r);
    bk[r] = ldx<F32>(bqkv, 64 + w * 16 + quad * 4 + r);
  }
  const float bv = ldx<F32>(bqkv, 128 + w * 16 + li);
#pragma unroll
  for (int nb = 0; nb < 4; ++nb) {
    f32x4 dq = {0.f, 0.f, 0.f, 0.f}, dk = dq, dv = dq;
    dq = mfma32(Wf[0][0], Hf[nb][0], dq);
    dq = mfma32(Wf[0][1], Hf[nb][1], dq);
    dk = mfma32(Wf[1][0], Hf[nb][0], dk);
    dk = mfma32(Wf[1][1], Hf[nb][1], dk);
    dv = mfma32(Hf[nb][0], Wf[2][0], dv);
    dv = mfma32(Hf[nb][1], Wf[2][1], dv);
    union { ushort4 u; short s[4]; } pq, pk_, pv;
#pragma unroll
    for (int r = 0; r < 4; ++r) {
      pq.s[r] = f2bs((dq[r] + bq[r]) * C2_);
      pk_.s[r] = f2bs(dk[r] + bk[r]);
      pv.s[r] = f2bs(dv[r] + bv);
    }
    const int nbg = tj * 4 + nb;
    // q/k: lane holds X[c_out = w*16+quad*4+r][token = nb*16+li]
    const size_t qko = ((((size_t)(b * 128 + (nbg >> 1))) * 4 + w) * 2 +
                        (quad >> 1)) * 256 +
                       ((nbg & 1) * 16 + li) * 8 + (quad & 1) * 4;
    *(ushort4*)&q[qko] = pq.u;
    *(ushort4*)&k[qko] = pk_.u;
    // v: lane holds V[c_out = w*16+li][token = nb*16+quad*4+r]
    const size_t vo = ((((size_t)(b * 256 + nbg)) * 2 + (w >> 1)) * 2 +
                       (quad & 1)) * 256 +
                      ((w & 1) * 16 + li) * 8 + (quad & 2) * 2;
    *(ushort4*)&v[vo] = pv.u;
  }
}
__global__ __launch_bounds__(256) void k_qkv(
    const void* __restrict__ x, const void* __restrict__ wqkv,
    const void* __restrict__ bqkv, const float* __restrict__ meanArr,
    const float* __restrict__ rstdArr, bf16* __restrict__ q,
    bf16* __restrict__ k, bf16* __restrict__ v, const int* __restrict__ flag) {
  __shared__ short HB[4096];
  if (*flag) qkv_body<true>(x, wqkv, bqkv, meanArr, rstdArr, q, k, v, HB);
  else qkv_body<false>(x, wqkv, bqkv, meanArr, rstdArr, q, k, v, HB);
}

// ---------------- Kernel 3: barrier-free attention + proj + residual --------
// ROUND-10 VERIFIED (92.5 us best): grid 256 = (b, qt64), 512 thr / 8 waves.
// Wave w streams 32-key chunks ci = w, w+8, ..., w+120; K/V fragments load
// straight to VGPRs, single-buffered. Per chunk: interleaved QK chains
// (sv0,sv1 overlap MFMA latency) -> prefetch K(next) -> exp (raw v_exp_f32)
// + bf16 pack both -> PV cluster under setprio(1) -> prefetch V(next).
// NO barriers in the loop. VGPR=124, no spill (round-12 diag).
template <bool F32>
__device__ __forceinline__ void attnproj_body(
    const bf16* __restrict__ qg, const bf16* __restrict__ kg,
    const bf16* __restrict__ vg, const void* __restrict__ xg,
    const void* __restrict__ wp, const void* __restrict__ bp,
    void* __restrict__ outv, float* MS, float* LSs, int b, int qt) {
  const int t = threadIdx.x, l = t & 63, w = t >> 6;
  const int hi = l >> 5, q31 = l & 31;

  short8 Qf[2][4];
#pragma unroll
  for (int qs = 0; qs < 2; ++qs)
#pragma unroll
    for (int cc = 0; cc < 4; ++cc)
      Qf[qs][cc] = *(const short8*)(qg +
          ((((size_t)(b * 128 + qt * 2 + qs)) * 4 + cc) * 2 + hi) * 256 +
          q31 * 8);

  f32x16 O[2][2];
#pragma unroll
  for (int qs = 0; qs < 2; ++qs)
#pragma unroll
    for (int ch = 0; ch < 2; ++ch)
#pragma unroll
      for (int r = 0; r < 16; ++r) O[qs][ch][r] = 0.f;
  float ls[2] = {0.f, 0.f};

  const bf16* kb = kg + ((size_t)b * 128) * 2048;  // per kh32: 4*2*256 = 2048
  const bf16* vb = vg + ((size_t)b * 256) * 1024;  // per kc16: 2*2*256 = 1024

  short8 Kf[4], Vf[4];
#pragma unroll
  for (int cc = 0; cc < 4; ++cc)
    Kf[cc] = *(const short8*)(kb + (((size_t)w * 4 + cc) * 2 + hi) * 256 + q31 * 8);
#pragma unroll
  for (int i = 0; i < 4; ++i)
    Vf[i] = *(const short8*)(vb + (((size_t)(w * 2 + (i >> 1)) * 2 + (i & 1)) * 2 + hi) * 256 + q31 * 8);

  for (int jp = 0; jp < 16; ++jp) {
    const int cn = w + 8 * (jp + 1);
    const bool pf = jp < 15;
    // ---- interleaved QK chains for both query-sets
    f32x16 sv0, sv1;
#pragma unroll
    for (int r = 0; r < 16; ++r) { sv0[r] = 0.f; sv1[r] = 0.f; }
#pragma unroll
    for (int cc = 0; cc < 4; ++cc) {
      sv0 = mfmaL(Kf[cc], Qf[0][cc], sv0);
      sv1 = mfmaL(Kf[cc], Qf[1][cc], sv1);
    }
    // ---- prefetch K(next) (Kf regs free after QK)
    if (pf) {
#pragma unroll
      for (int cc = 0; cc < 4; ++cc)
        Kf[cc] = *(const short8*)(kb + (((size_t)cn * 4 + cc) * 2 + hi) * 256 + q31 * 8);
    }
    // ---- softmax numerators (raw v_exp_f32) + bf16 pack, both query-sets
    short8 Pb0[2], Pb1[2];
    {
      float pv[16];
#pragma unroll
      for (int r = 0; r < 16; ++r) pv[r] = EXP2(sv0[r]);
      ls[0] += (((pv[0] + pv[1]) + (pv[2] + pv[3])) +
                ((pv[4] + pv[5]) + (pv[6] + pv[7]))) +
               (((pv[8] + pv[9]) + (pv[10] + pv[11])) +
                ((pv[12] + pv[13]) + (pv[14] + pv[15])));
      union { short8 v; __hip_bfloat162 h[4]; } u0, u1;
#pragma unroll
      for (int wd = 0; wd < 4; ++wd) {
        u0.h[wd] = __float22bfloat162_rn(make_float2(pv[2 * wd], pv[2 * wd + 1]));
        u1.h[wd] = __float22bfloat162_rn(make_float2(pv[8 + 2 * wd], pv[9 + 2 * wd]));
      }
      Pb0[0] = u0.v;
      Pb0[1] = u1.v;
    }
    {
      float pv[16];
#pragma unroll
      for (int r = 0; r < 16; ++r) pv[r] = EXP2(sv1[r]);
      ls[1] += (((pv[0] + pv[1]) + (pv[2] + pv[3])) +
                ((pv[4] + pv[5]) + (pv[6] + pv[7]))) +
               (((pv[8] + pv[9]) + (pv[10] + pv[11])) +
                ((pv[12] + pv[13]) + (pv[14] + pv[15])));
      union { short8 v; __hip_bfloat162 h[4]; } u0, u1;
#pragma unroll
      for (int wd = 0; wd < 4; ++wd) {
        u0.h[wd] = __float22bfloat162_rn(make_float2(pv[2 * wd], pv[2 * wd + 1]));
        u1.h[wd] = __float22bfloat162_rn(make_float2(pv[8 + 2 * wd], pv[9 + 2 * wd]));
      }
      Pb1[0] = u0.v;
      Pb1[1] = u1.v;
    }
    // ---- PV cluster (last read of Vf) under raised wave priority
    __builtin_amdgcn_s_setprio(1);
#pragma unroll
    for (int ch = 0; ch < 2; ++ch)
#pragma unroll
      for (int kc2 = 0; kc2 < 2; ++kc2) {
        O[0][ch] = mfmaL(Vf[kc2 * 2 + ch], Pb0[kc2], O[0][ch]);
        O[1][ch] = mfmaL(Vf[kc2 * 2 + ch], Pb1[kc2], O[1][ch]);
      }
    __builtin_amdgcn_s_setprio(0);
    // ---- prefetch V(next)
    if (pf) {
#pragma unroll
      for (int i = 0; i < 4; ++i)
        Vf[i] = *(const short8*)(vb + (((size_t)(cn * 2 + (i >> 1)) * 2 + (i & 1)) * 2 + hi) * 256 + q31 * 8);
    }
  }
  // lane l covers hi-half keys; lane l^32 (same q) covers the other half
#pragma unroll
  for (int qs = 0; qs < 2; ++qs) ls[qs] += __shfl_xor(ls[qs], 32, 64);

  // tree merge across 8 waves (LDS slots of 16KB; ls alongside)
  if (w >= 4) {
    float* S = MS + (w - 4) * 4096;
#pragma unroll
    for (int qs = 0; qs < 2; ++qs) {
#pragma unroll
      for (int ch = 0; ch < 2; ++ch)
#pragma unroll
        for (int r = 0; r < 16; ++r)
          S[((qs * 2 + ch) * 16 + r) * 64 + l] = O[qs][ch][r];
      LSs[(w - 4) * 128 + qs * 64 + l] = ls[qs];
    }
  }
  __syncthreads();
  if (w < 4) {
    const float* S = MS + w * 4096;
#pragma unroll
    for (int qs = 0; qs < 2; ++qs) {
#pragma unroll
      for (int ch = 0; ch < 2; ++ch)
#pragma unroll
        for (int r = 0; r < 16; ++r)
          O[qs][ch][r] += S[((qs * 2 + ch) * 16 + r) * 64 + l];
      ls[qs] += LSs[w * 128 + qs * 64 + l];
    }
  }
  __syncthreads();
  if (w == 2 || w == 3) {
    float* S = MS + (w - 2) * 4096;
#pragma unroll
    for (int qs = 0; qs < 2; ++qs) {
#pragma unroll
      for (int ch = 0; ch < 2; ++ch)
#pragma unroll
        for (int r = 0; r < 16; ++r)
          S[((qs * 2 + ch) * 16 + r) * 64 + l] = O[qs][ch][r];
      LSs[(w - 2) * 128 + qs * 64 + l] = ls[qs];
    }
  }
  __syncthreads();
  if (w < 2) {
    const float* S = MS + w * 4096;
#pragma unroll
    for (int qs = 0; qs < 2; ++qs) {
#pragma unroll
      for (int ch = 0; ch < 2; ++ch)
#pragma unroll
        for (int r = 0; r < 16; ++r)
          O[qs][ch][r] += S[((qs * 2 + ch) * 16 + r) * 64 + l];
      ls[qs] += LSs[w * 128 + qs * 64 + l];
    }
  }
  __syncthreads();
  if (w == 1) {
    float* S = MS;
#pragma unroll
    for (int qs = 0; qs < 2; ++qs) {
#pragma unroll
      for (int ch = 0; ch < 2; ++ch)
#pragma unroll
        for (int r = 0; r < 16; ++r)
          S[((qs * 2 + ch) * 16 + r) * 64 + l] = O[qs][ch][r];
      LSs[qs * 64 + l] = ls[qs];
    }
  }
  __syncthreads();
  bf16* HT = (bf16*)(MS + 2 * 4096);  // slot2 region (dead): h' [64 q][72 c]
  if (w == 0) {
    const float* S = MS;
#pragma unroll
    for (int qs = 0; qs < 2; ++qs) {
#pragma unroll
      for (int ch = 0; ch < 2; ++ch)
#pragma unroll
        for (int r = 0; r < 16; ++r)
          O[qs][ch][r] += S[((qs * 2 + ch) * 16 + r) * 64 + l];
      ls[qs] += LSs[qs * 64 + l];
      const float lv = 1.0f / ls[qs];
      const int qrow = qs * 32 + q31;
#pragma unroll
      for (int ch = 0; ch < 2; ++ch)
#pragma unroll
        for (int g = 0; g < 4; ++g) {
          union { ushort4 u; short s[4]; } pk_;
#pragma unroll
          for (int rr = 0; rr < 4; ++rr)
            pk_.s[rr] = f2bs(O[qs][ch][g * 4 + rr] * lv);
          // c = ch*32 + (r&3) + 8*(r>>2) + 4*hi
          *(ushort4*)&HT[qrow * 72 + ch * 32 + g * 8 + hi * 4] = pk_.u;
        }
    }
  }
  __syncthreads();
  // proj: out[o,n] = wp[o,:] . h'[:,n] + bp[o] + x[o,n]; 8 waves: (jb o) x (qh n)
  const int li = l & 15, quad = l >> 4;
  const int jb = w & 3, qh = w >> 2;
  short8 Wa[2];
#pragma unroll
  for (int ks = 0; ks < 2; ++ks)
    Wa[ks] = ld8<F32>(wp, (jb * 16 + li) * 64 + ks * 32 + quad * 8);
  float bpv[4];
#pragma unroll
  for (int r = 0; r < 4; ++r) bpv[r] = ldx<F32>(bp, jb * 16 + quad * 4 + r);
#pragma unroll
  for (int nb = 0; nb < 2; ++nb) {
    short8 Hf[2];
#pragma unroll
    for (int ks = 0; ks < 2; ++ks)
      Hf[ks] = *(const short8*)&HT[(qh * 32 + nb * 16 + li) * 72 + ks * 32 + quad * 8];
    f32x4 acc = {0.f, 0.f, 0.f, 0.f};
    acc = mfma32(Wa[0], Hf[0], acc);
    acc = mfma32(Wa[1], Hf[1], acc);
#pragma unroll
    for (int r = 0; r < 4; ++r) {
      const int o = jb * 16 + quad * 4 + r;
      const int n = qt * 64 + qh * 32 + nb * 16 + li;
      const size_t idx = ((size_t)(b * 64 + o)) * N_ + n;
      const float res = ldx<F32>(xg, idx) + acc[r] + bpv[r];
      if (F32) ((float*)outv)[idx] = res;
      else ((bf16*)outv)[idx] = __float2bfloat16(res);
    }
  }
}

__global__ __launch_bounds__(512, 2) void k_attnproj(
    const bf16* __restrict__ qg, const bf16* __restrict__ kg,
    const bf16* __restrict__ vg, const void* __restrict__ xg,
    const void* __restrict__ wp, const void* __restrict__ bp,
    const int* __restrict__ flag, void* __restrict__ outv) {
  __shared__ float MS[4 * 4096];   // 64 KB merge slots (slot2 reused as HT)
  __shared__ float LSs[4 * 128];   // 2 KB ls slots
  const int bid = blockIdx.x;
  const int x = bid & 7;            // XCD: each XCD pair serves one batch
  const int b = x >> 1, qt = (bid >> 3) * 2 + (x & 1);
  if (*flag)
    attnproj_body<true>(qg, kg, vg, xg, wp, bp, outv, MS, LSs, b, qt);
  else
    attnproj_body<false>(qg, kg, vg, xg, wp, bp, outv, MS, LSs, b, qt);
}

// ---------------- launcher --------------------------------------------------
extern "C" void kernel_launch(void* const* d_in, const int* in_sizes, int n_in,
                              void* d_out, int out_size, void* d_ws,
                              size_t ws_size, hipStream_t stream) {
  const void* x = d_in[0];
  const void* wqkv = d_in[1];
  const void* bqkv = d_in[2];
  const void* wproj = d_in[3];
  const void* bproj = d_in[4];

  char* ws = (char*)d_ws;
  float* meanArr = (float*)ws;                      // 1 KB
  float* rstdArr = (float*)(ws + 1024);             // 1 KB
  int* flag = (int*)(ws + 2048);
  bf16* q = (bf16*)(ws + 4096);                     // 2 MB
  bf16* k = (bf16*)(ws + 4096 + (2u << 20));        // 2 MB
  bf16* v = (bf16*)(ws + 4096 + (4u << 20));        // 2 MB

  k_stats<<<256, 256, 0, stream>>>(x, meanArr, rstdArr, flag);
  k_qkv<<<dim3(64, 4), 256, 0, stream>>>(x, wqkv, bqkv, meanArr, rstdArr, q, k,
                                         v, flag);
  k_attnproj<<<256, 512, 0, stream>>>(q, k, v, x, wproj, bproj, flag, d_out);
}